// Round 18
// baseline (157.365 us; speedup 1.0000x reference)
//
#include <hip/hip_runtime.h>
#include <hip/hip_bf16.h>

typedef __attribute__((ext_vector_type(8))) short bhalf8;   // 8 bf16 MFMA operand
typedef __attribute__((ext_vector_type(4))) float f32x4;
typedef __attribute__((ext_vector_type(8))) unsigned short u16x8;
typedef __attribute__((ext_vector_type(4))) unsigned short u16x4;

#define BDIM 2
#define SDIM 2048
#define DDIM 1024
#define HDIM 16
#define HDHD 64

// async global->LDS, 16B per lane; LDS dest is wave-uniform base + lane*16 (linear).
#define GLD16(gaddr, laddr)                                                          \
  __builtin_amdgcn_global_load_lds(                                                  \
      (const __attribute__((address_space(1))) unsigned int*)(gaddr),                \
      (__attribute__((address_space(3))) unsigned int*)(laddr), 16, 0, 0)

__device__ __forceinline__ unsigned short f2bf(float f) {
  unsigned u = __builtin_bit_cast(unsigned, f);
  u += 0x7fffu + ((u >> 16) & 1u);           // RNE
  return (unsigned short)(u >> 16);
}
// compiler-visible RNE cvt -> pairs into v_cvt_pk_bf16_f32 (m240: don't hand-write asm)
__device__ __forceinline__ unsigned short f2bfc(float f) {
  return __builtin_bit_cast(unsigned short, __float2bfloat16(f));
}
__device__ __forceinline__ float bf2f(unsigned short u) {
  return __builtin_bit_cast(float, (unsigned)u << 16);
}

// ---------------- elementwise f32 -> bf16 ----------------
__global__ __launch_bounds__(256) void cvt_hidden(const float* __restrict__ x,
                                                  unsigned short* __restrict__ y) {
  size_t i = ((size_t)blockIdx.x * 256 + threadIdx.x) * 4;
  f32x4 v = *(const f32x4*)(x + i);
  u16x4 o;
  o[0] = f2bf(v[0]); o[1] = f2bf(v[1]); o[2] = f2bf(v[2]); o[3] = f2bf(v[3]);
  *(u16x4*)(y + i) = o;
}

// ---------------- transpose + convert: W[R][C] f32 -> Wt[C][R] bf16 ----------------
__global__ __launch_bounds__(256) void transpose_cvt(const float* __restrict__ W,
                                                     unsigned short* __restrict__ Wt,
                                                     int R, int C) {
  __shared__ float tl[32][33];
  int rt = blockIdx.x * 32, ct = blockIdx.y * 32;
  int r8 = threadIdx.x >> 5, c = threadIdx.x & 31;
#pragma unroll
  for (int i = 0; i < 4; i++)
    tl[r8 + i * 8][c] = W[(size_t)(rt + r8 + i * 8) * C + ct + c];
  __syncthreads();
#pragma unroll
  for (int i = 0; i < 4; i++)
    Wt[(size_t)(ct + r8 + i * 8) * R + rt + c] = f2bf(tl[c][r8 + i * 8]);
}

// ------- W'^T[o][h*64+d] = sum_e P[h][d][e] * Wproj[h*64+e][o]  (bf16 out) -------
__global__ __launch_bounds__(256) void make_wproj(const float* __restrict__ proj,
                                                  const float* __restrict__ wproj,
                                                  unsigned short* __restrict__ WT) {
  int h = blockIdx.x, ot = blockIdx.y * 64;
  __shared__ float Pl[64][65];
  __shared__ float Wl[64][65];
  int t = threadIdx.x;
#pragma unroll
  for (int i = 0; i < 16; i++) {
    int idx = t + 256 * i;                  // 0..4095
    int a = idx >> 6, bc = idx & 63;
    Pl[a][bc] = proj[(size_t)h * 4096 + idx];
    Wl[a][bc] = wproj[(size_t)(h * 64 + a) * 1024 + ot + bc];
  }
  __syncthreads();
  int d = t & 63, ob = t >> 6;              // lanes vary d -> coalesced writes
#pragma unroll
  for (int i = 0; i < 16; i++) {
    int o = ob + i * 4;
    float acc = 0.f;
#pragma unroll
    for (int e = 0; e < 64; e++) acc += Pl[d][e] * Wl[e][o];
    WT[(size_t)(ot + o) * 1024 + h * 64 + d] = f2bf(acc);
  }
}

// ---------------- QKV GEMM: C[M,N]=A[M,K]@Bt[N,K]^T+bias, split into q/k/vT ----------------
// 2-phase double-buffered GLD16 (T3 minimum-2-phase): stage t+1 async into buf^1,
// compute t from buf, ONE barrier (vmcnt drain lands after MFMA). XOR-swizzled
// source + reads = conflict-free (R16 PMC: SQ_LDS_BANK_CONFLICT == 0).
// V stored TRANSPOSED [B,H,HD,S] (packed u16x4 store; attn stages V^T repack-free).
__global__ __launch_bounds__(256) void gemm_qkv(
    const unsigned short* __restrict__ A, const unsigned short* __restrict__ Bt,
    const float* __restrict__ bias,
    unsigned short* __restrict__ q, unsigned short* __restrict__ k,
    unsigned short* __restrict__ vT, int M, int N, int K) {
  __shared__ unsigned short As[2][128 * 64];   // double-buffered, linear+XOR-swizzled
  __shared__ unsigned short Bs[2][128 * 64];
  const int tid = threadIdx.x;
  const int orig = blockIdx.y * 24 + blockIdx.x;          // 0..767
  const int swz = (orig & 7) * 96 + (orig >> 3);          // bijective (768 = 8*96)
  const int m0 = (swz / 24) * 128, n0 = (swz % 24) * 128;
  f32x4 acc[4][4];
#pragma unroll
  for (int m = 0; m < 4; m++)
#pragma unroll
    for (int n = 0; n < 4; n++) acc[m][n] = f32x4{0.f, 0.f, 0.f, 0.f};
  const int w = tid >> 6, lane = tid & 63;
  const int wr = (w >> 1) * 64, wc = (w & 1) * 64;
  const int lrow = lane & 15, lg = lane >> 4;   // fragment row / k-group

  auto STAGE = [&](int bi, int kt) {
#pragma unroll
    for (int i = 0; i < 4; i++) {
      int cl = tid + 256 * i;               // linear chunk: lds byte = cl*16
      int r = cl >> 3, c = cl & 7;
      int sc = (c ^ (r & 7)) * 8;           // XOR-swizzled source col (elements)
      GLD16(A + (size_t)(m0 + r) * K + kt + sc, &As[bi][cl * 8]);
      GLD16(Bt + (size_t)(n0 + r) * K + kt + sc, &Bs[bi][cl * 8]);
    }
  };

  STAGE(0, 0);
  __syncthreads();                          // tile 0 resident
  int cur = 0;
  for (int kt = 0; kt < K; kt += 64) {
    if (kt + 64 < K) STAGE(cur ^ 1, kt + 64);   // async: lands during compute
#pragma unroll
    for (int kk = 0; kk < 2; kk++) {
      bhalf8 af[4], bfr[4];
#pragma unroll
      for (int m = 0; m < 4; m++) {
        int r = wr + m * 16 + lrow;
        int ch = r * 8 + ((kk * 4 + lg) ^ (r & 7));
        af[m] = *(const bhalf8*)(&As[cur][ch * 8]);
      }
#pragma unroll
      for (int n = 0; n < 4; n++) {
        int r = wc + n * 16 + lrow;
        int ch = r * 8 + ((kk * 4 + lg) ^ (r & 7));
        bfr[n] = *(const bhalf8*)(&Bs[cur][ch * 8]);
      }
#pragma unroll
      for (int m = 0; m < 4; m++)
#pragma unroll
        for (int n = 0; n < 4; n++)
          acc[m][n] = __builtin_amdgcn_mfma_f32_16x16x32_bf16(af[m], bfr[n], acc[m][n], 0, 0, 0);
    }
    __syncthreads();                        // one barrier/tile (drains staging)
    cur ^= 1;
  }
  const int g = lane >> 4, il = lane & 15;
#pragma unroll
  for (int m = 0; m < 4; m++) {
    int rowb = wr + m * 16 + 4 * g;
#pragma unroll
    for (int n = 0; n < 4; n++) {
      int col = n0 + wc + n * 16 + il;
      float bs = bias[col];
      int which = col >> 10, hh = (col >> 6) & 15, hd = col & 63;
      int row0 = m0 + rowb;
      int b = row0 >> 11, s0 = row0 & 2047;   // 4-row group never crosses b boundary
      if (which == 2) {
        u16x4 pv;
#pragma unroll
        for (int r = 0; r < 4; r++) pv[r] = f2bf(acc[m][n][r] + bs);
        *(u16x4*)(vT + ((size_t)(b * 16 + hh) * HDHD + hd) * SDIM + s0) = pv;
      } else {
#pragma unroll
        for (int r = 0; r < 4; r++) {
          float val = acc[m][n][r] + bs;
          size_t idx = ((size_t)(b * 16 + hh) * SDIM + s0 + r) * HDHD + hd;
          // q pre-scaled by 1/8 * log2(e) so attention can use native exp2
          unsigned short bv = f2bf(which == 0 ? val * 0.1803368801f : val);
          if (which == 0) q[idx] = bv;
          else k[idx] = bv;
        }
      }
    }
  }
}

// ---------------- output GEMM: BM=64, BN=128, 128 threads ----------------
__global__ __launch_bounds__(128) void gemm_out(
    const unsigned short* __restrict__ A, const unsigned short* __restrict__ Bt,
    const float* __restrict__ bias, float* __restrict__ Cf, int M, int N, int K) {
  __shared__ unsigned short As[64][72];
  __shared__ unsigned short Bs[128][72];
  const int tid = threadIdx.x;
  const int orig = blockIdx.y * 8 + blockIdx.x;           // 0..511
  const int swz = (orig & 7) * 64 + (orig >> 3);          // bijective (512 = 8*64)
  const int m0 = (swz / 8) * 64, n0 = (swz % 8) * 128;
  f32x4 acc[4][4];
#pragma unroll
  for (int m = 0; m < 4; m++)
#pragma unroll
    for (int n = 0; n < 4; n++) acc[m][n] = f32x4{0.f, 0.f, 0.f, 0.f};
  const int w = tid >> 6, lane = tid & 63;
  const int wc = w * 64;
  const int lrow = lane & 15, lk = (lane >> 4) * 8;

  for (int kt = 0; kt < K; kt += 64) {
    __syncthreads();
#pragma unroll
    for (int i = 0; i < 4; i++) {           // A: 512 chunks, 4/thread
      int cch = tid + 128 * i;
      int r = cch >> 3, c8 = cch & 7;
      *(u16x8*)(&As[r][c8 * 8]) = *(const u16x8*)(A + (size_t)(m0 + r) * K + kt + c8 * 8);
    }
#pragma unroll
    for (int i = 0; i < 8; i++) {           // B: 1024 chunks, 8/thread
      int cch = tid + 128 * i;
      int r = cch >> 3, c8 = cch & 7;
      *(u16x8*)(&Bs[r][c8 * 8]) = *(const u16x8*)(Bt + (size_t)(n0 + r) * K + kt + c8 * 8);
    }
    __syncthreads();
#pragma unroll
    for (int kk = 0; kk < 2; kk++) {
      bhalf8 af[4], bfr[4];
#pragma unroll
      for (int m = 0; m < 4; m++) af[m] = *(const bhalf8*)(&As[m * 16 + lrow][kk * 32 + lk]);
#pragma unroll
      for (int n = 0; n < 4; n++) bfr[n] = *(const bhalf8*)(&Bs[wc + n * 16 + lrow][kk * 32 + lk]);
#pragma unroll
      for (int m = 0; m < 4; m++)
#pragma unroll
        for (int n = 0; n < 4; n++)
          acc[m][n] = __builtin_amdgcn_mfma_f32_16x16x32_bf16(af[m], bfr[n], acc[m][n], 0, 0, 0);
    }
  }
  const int g = lane >> 4, il = lane & 15;
#pragma unroll
  for (int m = 0; m < 4; m++) {
    int rowb = m * 16 + 4 * g;
#pragma unroll
    for (int n = 0; n < 4; n++) {
      int col = n0 + wc + n * 16 + il;
      float bs = bias[col];
#pragma unroll
      for (int r = 0; r < 4; r++)
        Cf[(size_t)(m0 + rowb + r) * N + col] = acc[m][n][r] + bs;
    }
  }
}

// ============ split-KV causal flash attention, templated segment size ============
// Grid x=bh, y=31-qt, z=seg; FIXED SEGT-tile windows (R11 lesson). P = exp2(s).
// V PRE-TRANSPOSED [B,H,HD,S] -> V staging identical to K staging (no repack VALU).
// Partials UNNORMALIZED (O, l). setprio(1) around MFMA clusters (T5: independent
// 2-wave blocks at different phases = the m191 regime, not R3's lockstep case).
template <int SEGT>
__global__ __launch_bounds__(128, 3) void attn_partial(const unsigned short* __restrict__ Q,
                                                       const unsigned short* __restrict__ Kb,
                                                       const unsigned short* __restrict__ VbT,
                                                       unsigned short* __restrict__ PO,
                                                       float* __restrict__ ML) {
  __shared__ unsigned short Ks[64][72];        // K rows (also reused as O bounce)
  __shared__ unsigned short Vt[64][72];        // V^T rows: Vt[d][k]
  __shared__ unsigned short Ps[2][32][72];     // per-wave P tile (32 q x 64 k)
  const int bh = blockIdx.x;                   // b*16+h
  const int qt = 31 - blockIdx.y;              // longest q-tiles dispatch first
  const int seg = blockIdx.z;
  const int aS = qt / SEGT, bS = qt % SEGT;
  const int nseg = aS + 1;                     // ceil((qt+1)/SEGT)
  if (seg >= nseg) return;
  const int k0 = seg * SEGT;
  const int k1 = min(k0 + SEGT, qt + 1);

  const int tid = threadIdx.x;                 // 0..127
  const int w = tid >> 6, lane = tid & 63;
  const int g = lane >> 4, il = lane & 15;
  const int qbase = qt * 64 + w * 32;          // this wave's 32 q-rows
  const size_t bhS = (size_t)bh * SDIM;

  // Q fragments (pre-scaled by log2e/8): 2 col-frags x 2 d-chunks
  bhalf8 qf[2][2];
#pragma unroll
  for (int f = 0; f < 2; f++) {
    const unsigned short* qp = Q + (bhS + qbase + f * 16 + il) * HDHD + g * 8;
    qf[f][0] = *(const bhalf8*)(qp);
    qf[f][1] = *(const bhalf8*)(qp + 32);
  }
  f32x4 oacc[2][4];                            // O^T[d=df*16+4g+r][q-col]
#pragma unroll
  for (int f = 0; f < 2; f++)
#pragma unroll
    for (int i = 0; i < 4; i++) oacc[f][i] = f32x4{0.f, 0.f, 0.f, 0.f};
  float lrun[2] = {0.f, 0.f};

  // staging indices (128 threads): identical pattern for K and V^T
  const int srow = tid >> 1;                   // row 0..63 (K: s-row; V: d-row)
  const int schk = (tid & 1) * 32;             // 32-u16 half-row

  // ---- prefetch registers: tile k0 ----
  u16x8 kr[4], vrr[4];
  {
    const unsigned short* ksrc = Kb + (bhS + (size_t)k0 * 64 + srow) * HDHD + schk;
#pragma unroll
    for (int i = 0; i < 4; i++) kr[i] = *(const u16x8*)(ksrc + i * 8);
    const unsigned short* vsrc = VbT + ((size_t)bh * HDHD + srow) * SDIM + (size_t)k0 * 64 + schk;
#pragma unroll
    for (int i = 0; i < 4; i++) vrr[i] = *(const u16x8*)(vsrc + i * 8);
  }

  for (int kt = k0; kt < k1; kt++) {
    __syncthreads();
    // --- stage current tile from regs into LDS (K and V^T symmetric) ---
#pragma unroll
    for (int i = 0; i < 4; i++) *(u16x8*)(&Ks[srow][schk + i * 8]) = kr[i];
#pragma unroll
    for (int i = 0; i < 4; i++) *(u16x8*)(&Vt[srow][schk + i * 8]) = vrr[i];
    // --- issue next-tile loads (land during this tile's compute) ---
    if (kt + 1 < k1) {
      const unsigned short* ksrc = Kb + (bhS + (size_t)(kt + 1) * 64 + srow) * HDHD + schk;
#pragma unroll
      for (int i = 0; i < 4; i++) kr[i] = *(const u16x8*)(ksrc + i * 8);
      const unsigned short* vsrc = VbT + ((size_t)bh * HDHD + srow) * SDIM + (size_t)(kt + 1) * 64 + schk;
#pragma unroll
      for (int i = 0; i < 4; i++) vrr[i] = *(const u16x8*)(vsrc + i * 8);
    }
    __syncthreads();
    // --- S^T = mfma(K, Q): lane il holds S^T[k=c*16+4g+r][q=f*16+il] ---
    f32x4 s[2][4];
#pragma unroll
    for (int f = 0; f < 2; f++)
#pragma unroll
      for (int c = 0; c < 4; c++) s[f][c] = f32x4{0.f, 0.f, 0.f, 0.f};
    __builtin_amdgcn_s_setprio(1);
#pragma unroll
    for (int c = 0; c < 4; c++) {
      bhalf8 kf0 = *(const bhalf8*)(&Ks[c * 16 + il][g * 8]);
      bhalf8 kf1 = *(const bhalf8*)(&Ks[c * 16 + il][32 + g * 8]);
#pragma unroll
      for (int f = 0; f < 2; f++) {
        s[f][c] = __builtin_amdgcn_mfma_f32_16x16x32_bf16(kf0, qf[f][0], s[f][c], 0, 0, 0);
        s[f][c] = __builtin_amdgcn_mfma_f32_16x16x32_bf16(kf1, qf[f][1], s[f][c], 0, 0, 0);
      }
    }
    __builtin_amdgcn_s_setprio(0);
    // --- per-lane softmax accumulate (P = exp2(s)) ---
    if (kt == qt) {
      // diagonal tile: causal masking
#pragma unroll
      for (int f = 0; f < 2; f++) {
        const int thr = w * 32 + f * 16 + il;
        float rs = 0.f;
#pragma unroll
        for (int c = 0; c < 4; c++) {
          u16x4 pk;
#pragma unroll
          for (int r = 0; r < 4; r++) {
            float v = s[f][c][r];
            if (c * 16 + 4 * g + r > thr) v = -1e30f;
            float pv = exp2f(v);
            rs += pv;
            pk[r] = f2bfc(pv);
          }
          *(u16x4*)(&Ps[w][f * 16 + il][c * 16 + 4 * g]) = pk;
        }
        rs += __shfl_xor(rs, 16);
        rs += __shfl_xor(rs, 32);
        lrun[f] += rs;
      }
    } else {
      // interior tile: no masking
#pragma unroll
      for (int f = 0; f < 2; f++) {
        float rs = 0.f;
#pragma unroll
        for (int c = 0; c < 4; c++) {
          u16x4 pk;
#pragma unroll
          for (int r = 0; r < 4; r++) {
            float pv = exp2f(s[f][c][r]);
            rs += pv;
            pk[r] = f2bfc(pv);                 // pairs into v_cvt_pk_bf16_f32
          }
          *(u16x4*)(&Ps[w][f * 16 + il][c * 16 + 4 * g]) = pk;
        }
        rs += __shfl_xor(rs, 16);
        rs += __shfl_xor(rs, 32);
        lrun[f] += rs;
      }
    }
    // --- O^T += mfma(V^T, P) ---
    __builtin_amdgcn_s_setprio(1);
#pragma unroll
    for (int kk = 0; kk < 2; kk++) {
      bhalf8 pf0 = *(const bhalf8*)(&Ps[w][il][kk * 32 + g * 8]);
      bhalf8 pf1 = *(const bhalf8*)(&Ps[w][16 + il][kk * 32 + g * 8]);
#pragma unroll
      for (int df = 0; df < 4; df++) {
        bhalf8 vf = *(const bhalf8*)(&Vt[df * 16 + il][kk * 32 + g * 8]);
        oacc[0][df] = __builtin_amdgcn_mfma_f32_16x16x32_bf16(vf, pf0, oacc[0][df], 0, 0, 0);
        oacc[1][df] = __builtin_amdgcn_mfma_f32_16x16x32_bf16(vf, pf1, oacc[1][df], 0, 0, 0);
      }
    }
    __builtin_amdgcn_s_setprio(0);
  }
  // --- epilogue: UNNORMALIZED partial O (via LDS transpose) + l ---
  const int PB = (SEGT == 8) ? 80 : 144;       // per-bh partial count
  const int base = SEGT * (aS * (aS + 1) / 2) + bS * (aS + 1);
  const int pidx = bh * PB + base + seg;
  __syncthreads();
#pragma unroll
  for (int f = 0; f < 2; f++) {
#pragma unroll
    for (int df = 0; df < 4; df++) {
      u16x4 o;
#pragma unroll
      for (int r = 0; r < 4; r++) o[r] = f2bfc(oacc[f][df][r]);
      *(u16x4*)(&Ks[w * 32 + f * 16 + il][df * 16 + 4 * g]) = o;
    }
  }
  if (g == 0) {
#pragma unroll
    for (int f = 0; f < 2; f++)
      ML[(size_t)pidx * 64 + w * 32 + f * 16 + il] = lrun[f];
  }
  __syncthreads();
  {
    const int row = tid >> 1, half = (tid & 1) * 32;
    unsigned short* dst = PO + (size_t)pidx * 4096 + (size_t)row * 64 + half;
#pragma unroll
    for (int c8 = 0; c8 < 4; c8++)
      *(u16x8*)(dst + c8 * 8) = *(const u16x8*)(&Ks[row][half + c8 * 8]);
  }
}

// combine <= 32/SEGT segments per (bh, q-tile): O = sum(O_s) / sum(l_s)
template <int SEGT>
__global__ __launch_bounds__(256) void attn_reduce(const unsigned short* __restrict__ PO,
                                                   const float* __restrict__ ML,
                                                   unsigned short* __restrict__ Om) {
  constexpr int NMAX = 32 / SEGT;
  const int bh = blockIdx.x, qt = blockIdx.y;
  const int aS = qt / SEGT, bS = qt % SEGT;
  const int nseg = aS + 1;
  const int PB = (SEGT == 8) ? 80 : 144;
  const int base = bh * PB + SEGT * (aS * (aS + 1) / 2) + bS * (aS + 1);
  const int t = threadIdx.x;
  const int r = t >> 2, dc = (t & 3) * 16;
  float L = 0.f;
  float O[16];
#pragma unroll
  for (int j = 0; j < 16; j++) O[j] = 0.f;
#pragma unroll
  for (int s = 0; s < NMAX; s++) {
    if (s < nseg) {
      L += ML[(size_t)(base + s) * 64 + r];
      const unsigned short* p = PO + (size_t)(base + s) * 4096 + r * 64 + dc;
      u16x8 p0 = *(const u16x8*)p, p1 = *(const u16x8*)(p + 8);
#pragma unroll
      for (int j = 0; j < 8; j++) O[j] += bf2f(p0[j]);
#pragma unroll
      for (int j = 0; j < 8; j++) O[8 + j] += bf2f(p1[j]);
    }
  }
  float inv = 1.f / L;
  const int b = bh >> 4, h = bh & 15;
  size_t orow = ((size_t)b * SDIM + qt * 64 + r) * DDIM + h * HDHD + dc;
  u16x8 o0, o1;
#pragma unroll
  for (int j = 0; j < 8; j++) o0[j] = f2bfc(O[j] * inv);
#pragma unroll
  for (int j = 0; j < 8; j++) o1[j] = f2bfc(O[8 + j] * inv);
  *(u16x8*)(Om + orow) = o0;
  *(u16x8*)(Om + orow + 8) = o1;
}

// ---- fallback (small ws): direct swapped kernel, P = exp2(s), V^T layout ----
__global__ __launch_bounds__(128, 2) void attn_direct(const unsigned short* __restrict__ Q,
                                                      const unsigned short* __restrict__ Kb,
                                                      const unsigned short* __restrict__ VbT,
                                                      unsigned short* __restrict__ Om) {
  __shared__ unsigned short Ks[64][72];
  __shared__ unsigned short Vt[64][72];
  __shared__ unsigned short Ps[2][32][72];
  const int bh = blockIdx.x;
  const int qt = 31 - blockIdx.y;
  const int tid = threadIdx.x;
  const int w = tid >> 6, lane = tid & 63;
  const int g = lane >> 4, il = lane & 15;
  const int qbase = qt * 64 + w * 32;
  const size_t bhS = (size_t)bh * SDIM;
  bhalf8 qf[2][2];
#pragma unroll
  for (int f = 0; f < 2; f++) {
    const unsigned short* qp = Q + (bhS + qbase + f * 16 + il) * HDHD + g * 8;
    qf[f][0] = *(const bhalf8*)(qp);
    qf[f][1] = *(const bhalf8*)(qp + 32);
  }
  f32x4 oacc[2][4];
#pragma unroll
  for (int f = 0; f < 2; f++)
#pragma unroll
    for (int i = 0; i < 4; i++) oacc[f][i] = f32x4{0.f, 0.f, 0.f, 0.f};
  float lrun[2] = {0.f, 0.f};
  const int srow = tid >> 1, schk = (tid & 1) * 32;
  const int nt = qt + 1;
  for (int kt = 0; kt < nt; kt++) {
    __syncthreads();
    {
      const unsigned short* ksrc = Kb + (bhS + (size_t)kt * 64 + srow) * HDHD + schk;
#pragma unroll
      for (int i = 0; i < 4; i++) *(u16x8*)(&Ks[srow][schk + i * 8]) = *(const u16x8*)(ksrc + i * 8);
      const unsigned short* vsrc = VbT + ((size_t)bh * HDHD + srow) * SDIM + (size_t)kt * 64 + schk;
#pragma unroll
      for (int i = 0; i < 4; i++) *(u16x8*)(&Vt[srow][schk + i * 8]) = *(const u16x8*)(vsrc + i * 8);
    }
    __syncthreads();
    f32x4 s[2][4];
#pragma unroll
    for (int f = 0; f < 2; f++)
#pragma unroll
      for (int c = 0; c < 4; c++) s[f][c] = f32x4{0.f, 0.f, 0.f, 0.f};
#pragma unroll
    for (int c = 0; c < 4; c++) {
      bhalf8 kf0 = *(const bhalf8*)(&Ks[c * 16 + il][g * 8]);
      bhalf8 kf1 = *(const bhalf8*)(&Ks[c * 16 + il][32 + g * 8]);
#pragma unroll
      for (int f = 0; f < 2; f++) {
        s[f][c] = __builtin_amdgcn_mfma_f32_16x16x32_bf16(kf0, qf[f][0], s[f][c], 0, 0, 0);
        s[f][c] = __builtin_amdgcn_mfma_f32_16x16x32_bf16(kf1, qf[f][1], s[f][c], 0, 0, 0);
      }
    }
    const bool diag = (kt == qt);
#pragma unroll
    for (int f = 0; f < 2; f++) {
      const int thr = w * 32 + f * 16 + il;
      float rs = 0.f;
#pragma unroll
      for (int c = 0; c < 4; c++) {
        u16x4 pk;
#pragma unroll
        for (int r = 0; r < 4; r++) {
          float v = s[f][c][r];
          if (diag && (c * 16 + 4 * g + r > thr)) v = -1e30f;
          float pv = exp2f(v);
          rs += pv;
          pk[r] = f2bfc(pv);
        }
        *(u16x4*)(&Ps[w][f * 16 + il][c * 16 + 4 * g]) = pk;
      }
      rs += __shfl_xor(rs, 16);
      rs += __shfl_xor(rs, 32);
      lrun[f] += rs;
    }
#pragma unroll
    for (int kk = 0; kk < 2; kk++) {
      bhalf8 pf0 = *(const bhalf8*)(&Ps[w][il][kk * 32 + g * 8]);
      bhalf8 pf1 = *(const bhalf8*)(&Ps[w][16 + il][kk * 32 + g * 8]);
#pragma unroll
      for (int df = 0; df < 4; df++) {
        bhalf8 vf = *(const bhalf8*)(&Vt[df * 16 + il][kk * 32 + g * 8]);
        oacc[0][df] = __builtin_amdgcn_mfma_f32_16x16x32_bf16(vf, pf0, oacc[0][df], 0, 0, 0);
        oacc[1][df] = __builtin_amdgcn_mfma_f32_16x16x32_bf16(vf, pf1, oacc[1][df], 0, 0, 0);
      }
    }
  }
  __syncthreads();
#pragma unroll
  for (int f = 0; f < 2; f++) {
    float inv = 1.f / lrun[f];
#pragma unroll
    for (int df = 0; df < 4; df++) {
      u16x4 o;
#pragma unroll
      for (int r = 0; r < 4; r++) o[r] = f2bfc(oacc[f][df][r] * inv);
      *(u16x4*)(&Ks[w * 32 + f * 16 + il][df * 16 + 4 * g]) = o;
    }
  }
  __syncthreads();
  {
    const int row = tid >> 1, half = (tid & 1) * 32;
    const int b = bh >> 4, h = bh & 15;
    size_t obase = ((size_t)b * SDIM + qt * 64 + row) * DDIM + h * HDHD + half;
#pragma unroll
    for (int c8 = 0; c8 < 4; c8++)
      *(u16x8*)(Om + obase + c8 * 8) = *(const u16x8*)(&Ks[row][half + c8 * 8]);
  }
}

extern "C" void kernel_launch(void* const* d_in, const int* in_sizes, int n_in,
                              void* d_out, int out_size, void* d_ws, size_t ws_size,
                              hipStream_t stream) {
  const float* hidden = (const float*)d_in[0];
  const float* attn_w = (const float*)d_in[1];
  const float* attn_b = (const float*)d_in[2];
  const float* proj_w = (const float*)d_in[3];
  const float* proj_b = (const float*)d_in[4];
  const float* projectors = (const float*)d_in[5];
  float* out = (float*)d_out;
  char* ws = (char*)d_ws;
  (void)in_sizes; (void)n_in; (void)out_size;

  unsigned short* hseq   = (unsigned short*)(ws);               // [4096][1024] bf16  8 MB
  unsigned short* wqkvT  = (unsigned short*)(ws + 8388608);     // [3072][1024] bf16  6 MB
  unsigned short* qb     = (unsigned short*)(ws + 14680064);    // [B,H,S,HD] bf16    8 MB
  unsigned short* kb     = (unsigned short*)(ws + 23068672);    // 8 MB
  unsigned short* vbT    = (unsigned short*)(ws + 31457280);    // [B,H,HD,S] bf16    8 MB
  unsigned short* attnM  = (unsigned short*)(ws + 39845888);    // [4096][1024] bf16  8 MB
  unsigned short* wprojT = (unsigned short*)(ws + 48234496);    // [1024][1024] bf16  2 MB
  unsigned short* PO     = (unsigned short*)(ws + 50331648);    // partials (bf16)
  float* ML8 = (float*)(ws + 71303168);
  float* ML4 = (float*)(ws + 88080384);
  const size_t need8 = 71303168ull + 655360ull;
  const size_t need4 = 88080384ull + 1179648ull;

  cvt_hidden<<<dim3(4096), dim3(256), 0, stream>>>(hidden, hseq);
  transpose_cvt<<<dim3(32, 96), dim3(256), 0, stream>>>(attn_w, wqkvT, 1024, 3072);
  make_wproj<<<dim3(16, 16), dim3(256), 0, stream>>>(projectors, proj_w, wprojT);
  gemm_qkv<<<dim3(24, 32), dim3(256), 0, stream>>>(hseq, wqkvT, attn_b,
                                                   qb, kb, vbT, 4096, 3072, 1024);
  if (ws_size >= need4) {
    attn_partial<4><<<dim3(32, 32, 8), dim3(128), 0, stream>>>(qb, kb, vbT, PO, ML4);
    attn_reduce<4><<<dim3(32, 32), dim3(256), 0, stream>>>(PO, ML4, attnM);
  } else if (ws_size >= need8) {
    attn_partial<8><<<dim3(32, 32, 4), dim3(128), 0, stream>>>(qb, kb, vbT, PO, ML8);
    attn_reduce<8><<<dim3(32, 32), dim3(256), 0, stream>>>(PO, ML8, attnM);
  } else {
    attn_direct<<<dim3(32, 32), dim3(128), 0, stream>>>(qb, kb, vbT, attnM);
  }
  gemm_out<<<dim3(8, 64), dim3(128), 0, stream>>>(attnM, wprojT, proj_b, out,
                                                  4096, 1024, 1024);
}

// Round 19
// 154.446 us; speedup vs baseline: 1.0189x; 1.0189x over previous
//
#include <hip/hip_runtime.h>
#include <hip/hip_bf16.h>

typedef __attribute__((ext_vector_type(8))) short bhalf8;   // 8 bf16 MFMA operand
typedef __attribute__((ext_vector_type(4))) float f32x4;
typedef __attribute__((ext_vector_type(8))) unsigned short u16x8;
typedef __attribute__((ext_vector_type(4))) unsigned short u16x4;

#define BDIM 2
#define SDIM 2048
#define DDIM 1024
#define HDIM 16
#define HDHD 64

// async global->LDS, 16B per lane; LDS dest is wave-uniform base + lane*16 (linear).
#define GLD16(gaddr, laddr)                                                          \
  __builtin_amdgcn_global_load_lds(                                                  \
      (const __attribute__((address_space(1))) unsigned int*)(gaddr),                \
      (__attribute__((address_space(3))) unsigned int*)(laddr), 16, 0, 0)

__device__ __forceinline__ unsigned short f2bf(float f) {
  unsigned u = __builtin_bit_cast(unsigned, f);
  u += 0x7fffu + ((u >> 16) & 1u);           // RNE
  return (unsigned short)(u >> 16);
}
// compiler-visible RNE cvt -> pairs into v_cvt_pk_bf16_f32 (m240: don't hand-write asm)
__device__ __forceinline__ unsigned short f2bfc(float f) {
  return __builtin_bit_cast(unsigned short, __float2bfloat16(f));
}
__device__ __forceinline__ float bf2f(unsigned short u) {
  return __builtin_bit_cast(float, (unsigned)u << 16);
}

// ---------------- elementwise f32 -> bf16 ----------------
__global__ __launch_bounds__(256) void cvt_hidden(const float* __restrict__ x,
                                                  unsigned short* __restrict__ y) {
  size_t i = ((size_t)blockIdx.x * 256 + threadIdx.x) * 4;
  f32x4 v = *(const f32x4*)(x + i);
  u16x4 o;
  o[0] = f2bf(v[0]); o[1] = f2bf(v[1]); o[2] = f2bf(v[2]); o[3] = f2bf(v[3]);
  *(u16x4*)(y + i) = o;
}

// ---------------- transpose + convert: W[R][C] f32 -> Wt[C][R] bf16 ----------------
__global__ __launch_bounds__(256) void transpose_cvt(const float* __restrict__ W,
                                                     unsigned short* __restrict__ Wt,
                                                     int R, int C) {
  __shared__ float tl[32][33];
  int rt = blockIdx.x * 32, ct = blockIdx.y * 32;
  int r8 = threadIdx.x >> 5, c = threadIdx.x & 31;
#pragma unroll
  for (int i = 0; i < 4; i++)
    tl[r8 + i * 8][c] = W[(size_t)(rt + r8 + i * 8) * C + ct + c];
  __syncthreads();
#pragma unroll
  for (int i = 0; i < 4; i++)
    Wt[(size_t)(ct + r8 + i * 8) * R + rt + c] = f2bf(tl[c][r8 + i * 8]);
}

// ------- W'^T[o][h*64+d] = sum_e P[h][d][e] * Wproj[h*64+e][o]  (bf16 out) -------
__global__ __launch_bounds__(256) void make_wproj(const float* __restrict__ proj,
                                                  const float* __restrict__ wproj,
                                                  unsigned short* __restrict__ WT) {
  int h = blockIdx.x, ot = blockIdx.y * 64;
  __shared__ float Pl[64][65];
  __shared__ float Wl[64][65];
  int t = threadIdx.x;
#pragma unroll
  for (int i = 0; i < 16; i++) {
    int idx = t + 256 * i;                  // 0..4095
    int a = idx >> 6, bc = idx & 63;
    Pl[a][bc] = proj[(size_t)h * 4096 + idx];
    Wl[a][bc] = wproj[(size_t)(h * 64 + a) * 1024 + ot + bc];
  }
  __syncthreads();
  int d = t & 63, ob = t >> 6;              // lanes vary d -> coalesced writes
#pragma unroll
  for (int i = 0; i < 16; i++) {
    int o = ob + i * 4;
    float acc = 0.f;
#pragma unroll
    for (int e = 0; e < 64; e++) acc += Pl[d][e] * Wl[e][o];
    WT[(size_t)(ot + o) * 1024 + h * 64 + d] = f2bf(acc);
  }
}

// ---------------- QKV GEMM: C[M,N]=A[M,K]@Bt[N,K]^T+bias, split into q/k/vT ----------------
// R10-proven: GLD16 staging, linear LDS, XOR-swizzled source + reads (conflict-free, R16 PMC).
// V is stored TRANSPOSED [B,H,HD,S]: per fragment the 4 rows are 4 consecutive s at fixed
// (h,hd) -> one packed u16x4 store, and attention stages V^T with zero repack VALU.
__global__ __launch_bounds__(256) void gemm_qkv(
    const unsigned short* __restrict__ A, const unsigned short* __restrict__ Bt,
    const float* __restrict__ bias,
    unsigned short* __restrict__ q, unsigned short* __restrict__ k,
    unsigned short* __restrict__ vT, int M, int N, int K) {
  __shared__ unsigned short As[128 * 64];      // physically linear; logically swizzled
  __shared__ unsigned short Bs[128 * 64];
  const int tid = threadIdx.x;
  const int orig = blockIdx.y * 24 + blockIdx.x;          // 0..767
  const int swz = (orig & 7) * 96 + (orig >> 3);          // bijective (768 = 8*96)
  const int m0 = (swz / 24) * 128, n0 = (swz % 24) * 128;
  f32x4 acc[4][4];
#pragma unroll
  for (int m = 0; m < 4; m++)
#pragma unroll
    for (int n = 0; n < 4; n++) acc[m][n] = f32x4{0.f, 0.f, 0.f, 0.f};
  const int w = tid >> 6, lane = tid & 63;
  const int wr = (w >> 1) * 64, wc = (w & 1) * 64;
  const int lrow = lane & 15, lg = lane >> 4;   // fragment row / k-group

  for (int kt = 0; kt < K; kt += 64) {
    __syncthreads();                        // WAR: previous tile fully consumed
#pragma unroll
    for (int i = 0; i < 4; i++) {
      int cl = tid + 256 * i;               // linear chunk: lds byte = cl*16
      int r = cl >> 3, c = cl & 7;
      int sc = (c ^ (r & 7)) * 8;           // XOR-swizzled source col (elements)
      GLD16(A + (size_t)(m0 + r) * K + kt + sc, &As[cl * 8]);
      GLD16(Bt + (size_t)(n0 + r) * K + kt + sc, &Bs[cl * 8]);
    }
    __syncthreads();                        // drains vmcnt: tile resident
#pragma unroll
    for (int kk = 0; kk < 2; kk++) {
      bhalf8 af[4], bfr[4];
#pragma unroll
      for (int m = 0; m < 4; m++) {
        int r = wr + m * 16 + lrow;
        int ch = r * 8 + ((kk * 4 + lg) ^ (r & 7));
        af[m] = *(const bhalf8*)(&As[ch * 8]);
      }
#pragma unroll
      for (int n = 0; n < 4; n++) {
        int r = wc + n * 16 + lrow;
        int ch = r * 8 + ((kk * 4 + lg) ^ (r & 7));
        bfr[n] = *(const bhalf8*)(&Bs[ch * 8]);
      }
#pragma unroll
      for (int m = 0; m < 4; m++)
#pragma unroll
        for (int n = 0; n < 4; n++)
          acc[m][n] = __builtin_amdgcn_mfma_f32_16x16x32_bf16(af[m], bfr[n], acc[m][n], 0, 0, 0);
    }
  }
  const int g = lane >> 4, il = lane & 15;
#pragma unroll
  for (int m = 0; m < 4; m++) {
    int rowb = wr + m * 16 + 4 * g;
#pragma unroll
    for (int n = 0; n < 4; n++) {
      int col = n0 + wc + n * 16 + il;
      float bs = bias[col];
      int which = col >> 10, hh = (col >> 6) & 15, hd = col & 63;
      int row0 = m0 + rowb;
      int b = row0 >> 11, s0 = row0 & 2047;   // 4-row group never crosses b boundary
      if (which == 2) {
        u16x4 pv;
#pragma unroll
        for (int r = 0; r < 4; r++) pv[r] = f2bf(acc[m][n][r] + bs);
        *(u16x4*)(vT + ((size_t)(b * 16 + hh) * HDHD + hd) * SDIM + s0) = pv;
      } else {
#pragma unroll
        for (int r = 0; r < 4; r++) {
          float val = acc[m][n][r] + bs;
          size_t idx = ((size_t)(b * 16 + hh) * SDIM + s0 + r) * HDHD + hd;
          // q pre-scaled by 1/8 * log2(e) so attention can use native exp2
          unsigned short bv = f2bf(which == 0 ? val * 0.1803368801f : val);
          if (which == 0) q[idx] = bv;
          else k[idx] = bv;
        }
      }
    }
  }
}

// ---------------- output GEMM: BM=64, BN=128, 128 threads ----------------
__global__ __launch_bounds__(128) void gemm_out(
    const unsigned short* __restrict__ A, const unsigned short* __restrict__ Bt,
    const float* __restrict__ bias, float* __restrict__ Cf, int M, int N, int K) {
  __shared__ unsigned short As[64][72];
  __shared__ unsigned short Bs[128][72];
  const int tid = threadIdx.x;
  const int orig = blockIdx.y * 8 + blockIdx.x;           // 0..511
  const int swz = (orig & 7) * 64 + (orig >> 3);          // bijective (512 = 8*64)
  const int m0 = (swz / 8) * 64, n0 = (swz % 8) * 128;
  f32x4 acc[4][4];
#pragma unroll
  for (int m = 0; m < 4; m++)
#pragma unroll
    for (int n = 0; n < 4; n++) acc[m][n] = f32x4{0.f, 0.f, 0.f, 0.f};
  const int w = tid >> 6, lane = tid & 63;
  const int wc = w * 64;
  const int lrow = lane & 15, lk = (lane >> 4) * 8;

  for (int kt = 0; kt < K; kt += 64) {
    __syncthreads();
#pragma unroll
    for (int i = 0; i < 4; i++) {           // A: 512 chunks, 4/thread
      int cch = tid + 128 * i;
      int r = cch >> 3, c8 = cch & 7;
      *(u16x8*)(&As[r][c8 * 8]) = *(const u16x8*)(A + (size_t)(m0 + r) * K + kt + c8 * 8);
    }
#pragma unroll
    for (int i = 0; i < 8; i++) {           // B: 1024 chunks, 8/thread
      int cch = tid + 128 * i;
      int r = cch >> 3, c8 = cch & 7;
      *(u16x8*)(&Bs[r][c8 * 8]) = *(const u16x8*)(Bt + (size_t)(n0 + r) * K + kt + c8 * 8);
    }
    __syncthreads();
#pragma unroll
    for (int kk = 0; kk < 2; kk++) {
      bhalf8 af[4], bfr[4];
#pragma unroll
      for (int m = 0; m < 4; m++) af[m] = *(const bhalf8*)(&As[m * 16 + lrow][kk * 32 + lk]);
#pragma unroll
      for (int n = 0; n < 4; n++) bfr[n] = *(const bhalf8*)(&Bs[wc + n * 16 + lrow][kk * 32 + lk]);
#pragma unroll
      for (int m = 0; m < 4; m++)
#pragma unroll
        for (int n = 0; n < 4; n++)
          acc[m][n] = __builtin_amdgcn_mfma_f32_16x16x32_bf16(af[m], bfr[n], acc[m][n], 0, 0, 0);
    }
  }
  const int g = lane >> 4, il = lane & 15;
#pragma unroll
  for (int m = 0; m < 4; m++) {
    int rowb = m * 16 + 4 * g;
#pragma unroll
    for (int n = 0; n < 4; n++) {
      int col = n0 + wc + n * 16 + il;
      float bs = bias[col];
#pragma unroll
      for (int r = 0; r < 4; r++)
        Cf[(size_t)(m0 + rowb + r) * N + col] = acc[m][n][r] + bs;
    }
  }
}

// ============ split-KV causal flash attention, templated segment size ============
// Grid x=bh, y=31-qt, z=seg; FIXED SEGT-tile windows (R11 lesson). P = exp2(s)
// (softmax scale-invariant). V arrives PRE-TRANSPOSED [B,H,HD,S] -> V staging is
// identical in shape to K staging (contiguous b128 loads, zero repack VALU).
// Partials stored UNNORMALIZED (O, l); reduce computes sum(O)/sum(l).
template <int SEGT>
__global__ __launch_bounds__(128, 3) void attn_partial(const unsigned short* __restrict__ Q,
                                                       const unsigned short* __restrict__ Kb,
                                                       const unsigned short* __restrict__ VbT,
                                                       unsigned short* __restrict__ PO,
                                                       float* __restrict__ ML) {
  __shared__ unsigned short Ks[64][72];        // K rows (also reused as O bounce)
  __shared__ unsigned short Vt[64][72];        // V^T rows: Vt[d][k]
  __shared__ unsigned short Ps[2][32][72];     // per-wave P tile (32 q x 64 k)
  const int bh = blockIdx.x;                   // b*16+h
  const int qt = 31 - blockIdx.y;              // longest q-tiles dispatch first
  const int seg = blockIdx.z;
  const int aS = qt / SEGT, bS = qt % SEGT;
  const int nseg = aS + 1;                     // ceil((qt+1)/SEGT)
  if (seg >= nseg) return;
  const int k0 = seg * SEGT;
  const int k1 = min(k0 + SEGT, qt + 1);

  const int tid = threadIdx.x;                 // 0..127
  const int w = tid >> 6, lane = tid & 63;
  const int g = lane >> 4, il = lane & 15;
  const int qbase = qt * 64 + w * 32;          // this wave's 32 q-rows
  const size_t bhS = (size_t)bh * SDIM;

  // Q fragments (pre-scaled by log2e/8): 2 col-frags x 2 d-chunks
  bhalf8 qf[2][2];
#pragma unroll
  for (int f = 0; f < 2; f++) {
    const unsigned short* qp = Q + (bhS + qbase + f * 16 + il) * HDHD + g * 8;
    qf[f][0] = *(const bhalf8*)(qp);
    qf[f][1] = *(const bhalf8*)(qp + 32);
  }
  f32x4 oacc[2][4];                            // O^T[d=df*16+4g+r][q-col]
#pragma unroll
  for (int f = 0; f < 2; f++)
#pragma unroll
    for (int i = 0; i < 4; i++) oacc[f][i] = f32x4{0.f, 0.f, 0.f, 0.f};
  float lrun[2] = {0.f, 0.f};

  // staging indices (128 threads): identical pattern for K and V^T
  const int srow = tid >> 1;                   // row 0..63 (K: s-row; V: d-row)
  const int schk = (tid & 1) * 32;             // 32-u16 half-row

  // ---- prefetch registers: tile k0 ----
  u16x8 kr[4], vrr[4];
  {
    const unsigned short* ksrc = Kb + (bhS + (size_t)k0 * 64 + srow) * HDHD + schk;
#pragma unroll
    for (int i = 0; i < 4; i++) kr[i] = *(const u16x8*)(ksrc + i * 8);
    const unsigned short* vsrc = VbT + ((size_t)bh * HDHD + srow) * SDIM + (size_t)k0 * 64 + schk;
#pragma unroll
    for (int i = 0; i < 4; i++) vrr[i] = *(const u16x8*)(vsrc + i * 8);
  }

  for (int kt = k0; kt < k1; kt++) {
    __syncthreads();
    // --- stage current tile from regs into LDS (K and V^T symmetric) ---
#pragma unroll
    for (int i = 0; i < 4; i++) *(u16x8*)(&Ks[srow][schk + i * 8]) = kr[i];
#pragma unroll
    for (int i = 0; i < 4; i++) *(u16x8*)(&Vt[srow][schk + i * 8]) = vrr[i];
    // --- issue next-tile loads (land during this tile's compute) ---
    if (kt + 1 < k1) {
      const unsigned short* ksrc = Kb + (bhS + (size_t)(kt + 1) * 64 + srow) * HDHD + schk;
#pragma unroll
      for (int i = 0; i < 4; i++) kr[i] = *(const u16x8*)(ksrc + i * 8);
      const unsigned short* vsrc = VbT + ((size_t)bh * HDHD + srow) * SDIM + (size_t)(kt + 1) * 64 + schk;
#pragma unroll
      for (int i = 0; i < 4; i++) vrr[i] = *(const u16x8*)(vsrc + i * 8);
    }
    __syncthreads();
    // --- S^T = mfma(K, Q): lane il holds S^T[k=c*16+4g+r][q=f*16+il] ---
    f32x4 s[2][4];
#pragma unroll
    for (int f = 0; f < 2; f++)
#pragma unroll
      for (int c = 0; c < 4; c++) s[f][c] = f32x4{0.f, 0.f, 0.f, 0.f};
#pragma unroll
    for (int c = 0; c < 4; c++) {
      bhalf8 kf0 = *(const bhalf8*)(&Ks[c * 16 + il][g * 8]);
      bhalf8 kf1 = *(const bhalf8*)(&Ks[c * 16 + il][32 + g * 8]);
#pragma unroll
      for (int f = 0; f < 2; f++) {
        s[f][c] = __builtin_amdgcn_mfma_f32_16x16x32_bf16(kf0, qf[f][0], s[f][c], 0, 0, 0);
        s[f][c] = __builtin_amdgcn_mfma_f32_16x16x32_bf16(kf1, qf[f][1], s[f][c], 0, 0, 0);
      }
    }
    // --- per-lane softmax accumulate (P = exp2(s)) ---
    if (kt == qt) {
      // diagonal tile: causal masking
#pragma unroll
      for (int f = 0; f < 2; f++) {
        const int thr = w * 32 + f * 16 + il;
        float rs = 0.f;
#pragma unroll
        for (int c = 0; c < 4; c++) {
          u16x4 pk;
#pragma unroll
          for (int r = 0; r < 4; r++) {
            float v = s[f][c][r];
            if (c * 16 + 4 * g + r > thr) v = -1e30f;
            float pv = exp2f(v);
            rs += pv;
            pk[r] = f2bfc(pv);
          }
          *(u16x4*)(&Ps[w][f * 16 + il][c * 16 + 4 * g]) = pk;
        }
        rs += __shfl_xor(rs, 16);
        rs += __shfl_xor(rs, 32);
        lrun[f] += rs;
      }
    } else {
      // interior tile: no masking
#pragma unroll
      for (int f = 0; f < 2; f++) {
        float rs = 0.f;
#pragma unroll
        for (int c = 0; c < 4; c++) {
          u16x4 pk;
#pragma unroll
          for (int r = 0; r < 4; r++) {
            float pv = exp2f(s[f][c][r]);
            rs += pv;
            pk[r] = f2bfc(pv);                 // pairs into v_cvt_pk_bf16_f32
          }
          *(u16x4*)(&Ps[w][f * 16 + il][c * 16 + 4 * g]) = pk;
        }
        rs += __shfl_xor(rs, 16);
        rs += __shfl_xor(rs, 32);
        lrun[f] += rs;
      }
    }
    // --- O^T += mfma(V^T, P) ---
#pragma unroll
    for (int kk = 0; kk < 2; kk++) {
      bhalf8 pf0 = *(const bhalf8*)(&Ps[w][il][kk * 32 + g * 8]);
      bhalf8 pf1 = *(const bhalf8*)(&Ps[w][16 + il][kk * 32 + g * 8]);
#pragma unroll
      for (int df = 0; df < 4; df++) {
        bhalf8 vf = *(const bhalf8*)(&Vt[df * 16 + il][kk * 32 + g * 8]);
        oacc[0][df] = __builtin_amdgcn_mfma_f32_16x16x32_bf16(vf, pf0, oacc[0][df], 0, 0, 0);
        oacc[1][df] = __builtin_amdgcn_mfma_f32_16x16x32_bf16(vf, pf1, oacc[1][df], 0, 0, 0);
      }
    }
  }
  // --- epilogue: UNNORMALIZED partial O (via LDS transpose) + l ---
  const int PB = (SEGT == 8) ? 80 : 144;       // per-bh partial count
  const int base = SEGT * (aS * (aS + 1) / 2) + bS * (aS + 1);
  const int pidx = bh * PB + base + seg;
  __syncthreads();
#pragma unroll
  for (int f = 0; f < 2; f++) {
#pragma unroll
    for (int df = 0; df < 4; df++) {
      u16x4 o;
#pragma unroll
      for (int r = 0; r < 4; r++) o[r] = f2bfc(oacc[f][df][r]);
      *(u16x4*)(&Ks[w * 32 + f * 16 + il][df * 16 + 4 * g]) = o;
    }
  }
  if (g == 0) {
#pragma unroll
    for (int f = 0; f < 2; f++)
      ML[(size_t)pidx * 64 + w * 32 + f * 16 + il] = lrun[f];
  }
  __syncthreads();
  {
    const int row = tid >> 1, half = (tid & 1) * 32;
    unsigned short* dst = PO + (size_t)pidx * 4096 + (size_t)row * 64 + half;
#pragma unroll
    for (int c8 = 0; c8 < 4; c8++)
      *(u16x8*)(dst + c8 * 8) = *(const u16x8*)(&Ks[row][half + c8 * 8]);
  }
}

// combine <= 32/SEGT segments per (bh, q-tile): O = sum(O_s) / sum(l_s)
template <int SEGT>
__global__ __launch_bounds__(256) void attn_reduce(const unsigned short* __restrict__ PO,
                                                   const float* __restrict__ ML,
                                                   unsigned short* __restrict__ Om) {
  constexpr int NMAX = 32 / SEGT;
  const int bh = blockIdx.x, qt = blockIdx.y;
  const int aS = qt / SEGT, bS = qt % SEGT;
  const int nseg = aS + 1;
  const int PB = (SEGT == 8) ? 80 : 144;
  const int base = bh * PB + SEGT * (aS * (aS + 1) / 2) + bS * (aS + 1);
  const int t = threadIdx.x;
  const int r = t >> 2, dc = (t & 3) * 16;
  float L = 0.f;
  float O[16];
#pragma unroll
  for (int j = 0; j < 16; j++) O[j] = 0.f;
#pragma unroll
  for (int s = 0; s < NMAX; s++) {
    if (s < nseg) {
      L += ML[(size_t)(base + s) * 64 + r];
      const unsigned short* p = PO + (size_t)(base + s) * 4096 + r * 64 + dc;
      u16x8 p0 = *(const u16x8*)p, p1 = *(const u16x8*)(p + 8);
#pragma unroll
      for (int j = 0; j < 8; j++) O[j] += bf2f(p0[j]);
#pragma unroll
      for (int j = 0; j < 8; j++) O[8 + j] += bf2f(p1[j]);
    }
  }
  float inv = 1.f / L;
  const int b = bh >> 4, h = bh & 15;
  size_t orow = ((size_t)b * SDIM + qt * 64 + r) * DDIM + h * HDHD + dc;
  u16x8 o0, o1;
#pragma unroll
  for (int j = 0; j < 8; j++) o0[j] = f2bfc(O[j] * inv);
#pragma unroll
  for (int j = 0; j < 8; j++) o1[j] = f2bfc(O[8 + j] * inv);
  *(u16x8*)(Om + orow) = o0;
  *(u16x8*)(Om + orow + 8) = o1;
}

// ---- fallback (small ws): direct swapped kernel, P = exp2(s), V^T layout ----
__global__ __launch_bounds__(128, 2) void attn_direct(const unsigned short* __restrict__ Q,
                                                      const unsigned short* __restrict__ Kb,
                                                      const unsigned short* __restrict__ VbT,
                                                      unsigned short* __restrict__ Om) {
  __shared__ unsigned short Ks[64][72];
  __shared__ unsigned short Vt[64][72];
  __shared__ unsigned short Ps[2][32][72];
  const int bh = blockIdx.x;
  const int qt = 31 - blockIdx.y;
  const int tid = threadIdx.x;
  const int w = tid >> 6, lane = tid & 63;
  const int g = lane >> 4, il = lane & 15;
  const int qbase = qt * 64 + w * 32;
  const size_t bhS = (size_t)bh * SDIM;
  bhalf8 qf[2][2];
#pragma unroll
  for (int f = 0; f < 2; f++) {
    const unsigned short* qp = Q + (bhS + qbase + f * 16 + il) * HDHD + g * 8;
    qf[f][0] = *(const bhalf8*)(qp);
    qf[f][1] = *(const bhalf8*)(qp + 32);
  }
  f32x4 oacc[2][4];
#pragma unroll
  for (int f = 0; f < 2; f++)
#pragma unroll
    for (int i = 0; i < 4; i++) oacc[f][i] = f32x4{0.f, 0.f, 0.f, 0.f};
  float lrun[2] = {0.f, 0.f};
  const int srow = tid >> 1, schk = (tid & 1) * 32;
  const int nt = qt + 1;
  for (int kt = 0; kt < nt; kt++) {
    __syncthreads();
    {
      const unsigned short* ksrc = Kb + (bhS + (size_t)kt * 64 + srow) * HDHD + schk;
#pragma unroll
      for (int i = 0; i < 4; i++) *(u16x8*)(&Ks[srow][schk + i * 8]) = *(const u16x8*)(ksrc + i * 8);
      const unsigned short* vsrc = VbT + ((size_t)bh * HDHD + srow) * SDIM + (size_t)kt * 64 + schk;
#pragma unroll
      for (int i = 0; i < 4; i++) *(u16x8*)(&Vt[srow][schk + i * 8]) = *(const u16x8*)(vsrc + i * 8);
    }
    __syncthreads();
    f32x4 s[2][4];
#pragma unroll
    for (int f = 0; f < 2; f++)
#pragma unroll
      for (int c = 0; c < 4; c++) s[f][c] = f32x4{0.f, 0.f, 0.f, 0.f};
#pragma unroll
    for (int c = 0; c < 4; c++) {
      bhalf8 kf0 = *(const bhalf8*)(&Ks[c * 16 + il][g * 8]);
      bhalf8 kf1 = *(const bhalf8*)(&Ks[c * 16 + il][32 + g * 8]);
#pragma unroll
      for (int f = 0; f < 2; f++) {
        s[f][c] = __builtin_amdgcn_mfma_f32_16x16x32_bf16(kf0, qf[f][0], s[f][c], 0, 0, 0);
        s[f][c] = __builtin_amdgcn_mfma_f32_16x16x32_bf16(kf1, qf[f][1], s[f][c], 0, 0, 0);
      }
    }
    const bool diag = (kt == qt);
#pragma unroll
    for (int f = 0; f < 2; f++) {
      const int thr = w * 32 + f * 16 + il;
      float rs = 0.f;
#pragma unroll
      for (int c = 0; c < 4; c++) {
        u16x4 pk;
#pragma unroll
        for (int r = 0; r < 4; r++) {
          float v = s[f][c][r];
          if (diag && (c * 16 + 4 * g + r > thr)) v = -1e30f;
          float pv = exp2f(v);
          rs += pv;
          pk[r] = f2bfc(pv);
        }
        *(u16x4*)(&Ps[w][f * 16 + il][c * 16 + 4 * g]) = pk;
      }
      rs += __shfl_xor(rs, 16);
      rs += __shfl_xor(rs, 32);
      lrun[f] += rs;
    }
#pragma unroll
    for (int kk = 0; kk < 2; kk++) {
      bhalf8 pf0 = *(const bhalf8*)(&Ps[w][il][kk * 32 + g * 8]);
      bhalf8 pf1 = *(const bhalf8*)(&Ps[w][16 + il][kk * 32 + g * 8]);
#pragma unroll
      for (int df = 0; df < 4; df++) {
        bhalf8 vf = *(const bhalf8*)(&Vt[df * 16 + il][kk * 32 + g * 8]);
        oacc[0][df] = __builtin_amdgcn_mfma_f32_16x16x32_bf16(vf, pf0, oacc[0][df], 0, 0, 0);
        oacc[1][df] = __builtin_amdgcn_mfma_f32_16x16x32_bf16(vf, pf1, oacc[1][df], 0, 0, 0);
      }
    }
  }
  __syncthreads();
#pragma unroll
  for (int f = 0; f < 2; f++) {
    float inv = 1.f / lrun[f];
#pragma unroll
    for (int df = 0; df < 4; df++) {
      u16x4 o;
#pragma unroll
      for (int r = 0; r < 4; r++) o[r] = f2bfc(oacc[f][df][r] * inv);
      *(u16x4*)(&Ks[w * 32 + f * 16 + il][df * 16 + 4 * g]) = o;
    }
  }
  __syncthreads();
  {
    const int row = tid >> 1, half = (tid & 1) * 32;
    const int b = bh >> 4, h = bh & 15;
    size_t obase = ((size_t)b * SDIM + qt * 64 + row) * DDIM + h * HDHD + half;
#pragma unroll
    for (int c8 = 0; c8 < 4; c8++)
      *(u16x8*)(Om + obase + c8 * 8) = *(const u16x8*)(&Ks[row][half + c8 * 8]);
  }
}

extern "C" void kernel_launch(void* const* d_in, const int* in_sizes, int n_in,
                              void* d_out, int out_size, void* d_ws, size_t ws_size,
                              hipStream_t stream) {
  const float* hidden = (const float*)d_in[0];
  const float* attn_w = (const float*)d_in[1];
  const float* attn_b = (const float*)d_in[2];
  const float* proj_w = (const float*)d_in[3];
  const float* proj_b = (const float*)d_in[4];
  const float* projectors = (const float*)d_in[5];
  float* out = (float*)d_out;
  char* ws = (char*)d_ws;
  (void)in_sizes; (void)n_in; (void)out_size;

  unsigned short* hseq   = (unsigned short*)(ws);               // [4096][1024] bf16  8 MB
  unsigned short* wqkvT  = (unsigned short*)(ws + 8388608);     // [3072][1024] bf16  6 MB
  unsigned short* qb     = (unsigned short*)(ws + 14680064);    // [B,H,S,HD] bf16    8 MB
  unsigned short* kb     = (unsigned short*)(ws + 23068672);    // 8 MB
  unsigned short* vbT    = (unsigned short*)(ws + 31457280);    // [B,H,HD,S] bf16    8 MB
  unsigned short* attnM  = (unsigned short*)(ws + 39845888);    // [4096][1024] bf16  8 MB
  unsigned short* wprojT = (unsigned short*)(ws + 48234496);    // [1024][1024] bf16  2 MB
  unsigned short* PO     = (unsigned short*)(ws + 50331648);    // partials (bf16)
  float* ML8 = (float*)(ws + 71303168);
  float* ML4 = (float*)(ws + 88080384);
  const size_t need8 = 71303168ull + 655360ull;
  const size_t need4 = 88080384ull + 1179648ull;

  cvt_hidden<<<dim3(4096), dim3(256), 0, stream>>>(hidden, hseq);
  transpose_cvt<<<dim3(32, 96), dim3(256), 0, stream>>>(attn_w, wqkvT, 1024, 3072);
  make_wproj<<<dim3(16, 16), dim3(256), 0, stream>>>(projectors, proj_w, wprojT);
  gemm_qkv<<<dim3(24, 32), dim3(256), 0, stream>>>(hseq, wqkvT, attn_b,
                                                   qb, kb, vbT, 4096, 3072, 1024);
  if (ws_size >= need4) {
    attn_partial<4><<<dim3(32, 32, 8), dim3(128), 0, stream>>>(qb, kb, vbT, PO, ML4);
    attn_reduce<4><<<dim3(32, 32), dim3(256), 0, stream>>>(PO, ML4, attnM);
  } else if (ws_size >= need8) {
    attn_partial<8><<<dim3(32, 32, 4), dim3(128), 0, stream>>>(qb, kb, vbT, PO, ML8);
    attn_reduce<8><<<dim3(32, 32), dim3(256), 0, stream>>>(PO, ML8, attnM);
  } else {
    attn_direct<<<dim3(32, 32), dim3(128), 0, stream>>>(qb, kb, vbT, attnM);
  }
  gemm_out<<<dim3(8, 64), dim3(128), 0, stream>>>(attnM, wprojT, proj_b, out,
                                                  4096, 1024, 1024);
}

// Round 20
// 153.824 us; speedup vs baseline: 1.0230x; 1.0040x over previous
//
#include <hip/hip_runtime.h>
#include <hip/hip_bf16.h>

typedef __attribute__((ext_vector_type(8))) short bhalf8;   // 8 bf16 MFMA operand
typedef __attribute__((ext_vector_type(4))) float f32x4;
typedef __attribute__((ext_vector_type(8))) unsigned short u16x8;
typedef __attribute__((ext_vector_type(4))) unsigned short u16x4;

#define BDIM 2
#define SDIM 2048
#define DDIM 1024
#define HDIM 16
#define HDHD 64

// async global->LDS, 16B per lane; LDS dest is wave-uniform base + lane*16 (linear).
#define GLD16(gaddr, laddr)                                                          \
  __builtin_amdgcn_global_load_lds(                                                  \
      (const __attribute__((address_space(1))) unsigned int*)(gaddr),                \
      (__attribute__((address_space(3))) unsigned int*)(laddr), 16, 0, 0)

__device__ __forceinline__ unsigned short f2bf(float f) {
  unsigned u = __builtin_bit_cast(unsigned, f);
  u += 0x7fffu + ((u >> 16) & 1u);           // RNE
  return (unsigned short)(u >> 16);
}
// compiler-visible RNE cvt -> pairs into v_cvt_pk_bf16_f32 (m240: don't hand-write asm)
__device__ __forceinline__ unsigned short f2bfc(float f) {
  return __builtin_bit_cast(unsigned short, __float2bfloat16(f));
}
__device__ __forceinline__ float bf2f(unsigned short u) {
  return __builtin_bit_cast(float, (unsigned)u << 16);
}

// ---------------- elementwise f32 -> bf16 ----------------
__global__ __launch_bounds__(256) void cvt_hidden(const float* __restrict__ x,
                                                  unsigned short* __restrict__ y) {
  size_t i = ((size_t)blockIdx.x * 256 + threadIdx.x) * 4;
  f32x4 v = *(const f32x4*)(x + i);
  u16x4 o;
  o[0] = f2bf(v[0]); o[1] = f2bf(v[1]); o[2] = f2bf(v[2]); o[3] = f2bf(v[3]);
  *(u16x4*)(y + i) = o;
}

// ---------------- transpose + convert: W[R][C] f32 -> Wt[C][R] bf16 ----------------
__global__ __launch_bounds__(256) void transpose_cvt(const float* __restrict__ W,
                                                     unsigned short* __restrict__ Wt,
                                                     int R, int C) {
  __shared__ float tl[32][33];
  int rt = blockIdx.x * 32, ct = blockIdx.y * 32;
  int r8 = threadIdx.x >> 5, c = threadIdx.x & 31;
#pragma unroll
  for (int i = 0; i < 4; i++)
    tl[r8 + i * 8][c] = W[(size_t)(rt + r8 + i * 8) * C + ct + c];
  __syncthreads();
#pragma unroll
  for (int i = 0; i < 4; i++)
    Wt[(size_t)(ct + r8 + i * 8) * R + rt + c] = f2bf(tl[c][r8 + i * 8]);
}

// ------- W'^T[o][h*64+d] = sum_e P[h][d][e] * Wproj[h*64+e][o]  (bf16 out) -------
__global__ __launch_bounds__(256) void make_wproj(const float* __restrict__ proj,
                                                  const float* __restrict__ wproj,
                                                  unsigned short* __restrict__ WT) {
  int h = blockIdx.x, ot = blockIdx.y * 64;
  __shared__ float Pl[64][65];
  __shared__ float Wl[64][65];
  int t = threadIdx.x;
#pragma unroll
  for (int i = 0; i < 16; i++) {
    int idx = t + 256 * i;                  // 0..4095
    int a = idx >> 6, bc = idx & 63;
    Pl[a][bc] = proj[(size_t)h * 4096 + idx];
    Wl[a][bc] = wproj[(size_t)(h * 64 + a) * 1024 + ot + bc];
  }
  __syncthreads();
  int d = t & 63, ob = t >> 6;              // lanes vary d -> coalesced writes
#pragma unroll
  for (int i = 0; i < 16; i++) {
    int o = ob + i * 4;
    float acc = 0.f;
#pragma unroll
    for (int e = 0; e < 64; e++) acc += Pl[d][e] * Wl[e][o];
    WT[(size_t)(ot + o) * 1024 + h * 64 + d] = f2bf(acc);
  }
}

// ---------------- QKV GEMM: C[M,N]=A[M,K]@Bt[N,K]^T+bias, split into q/k/vT ----------------
// R10-proven: GLD16 staging, linear LDS, XOR-swizzled source + reads (conflict-free, R16 PMC).
// V is stored TRANSPOSED [B,H,HD,S]: per fragment the 4 rows are 4 consecutive s at fixed
// (h,hd) -> one packed u16x4 store, and attention stages V^T with zero repack VALU.
__global__ __launch_bounds__(256) void gemm_qkv(
    const unsigned short* __restrict__ A, const unsigned short* __restrict__ Bt,
    const float* __restrict__ bias,
    unsigned short* __restrict__ q, unsigned short* __restrict__ k,
    unsigned short* __restrict__ vT, int M, int N, int K) {
  __shared__ unsigned short As[128 * 64];      // physically linear; logically swizzled
  __shared__ unsigned short Bs[128 * 64];
  const int tid = threadIdx.x;
  const int orig = blockIdx.y * 24 + blockIdx.x;          // 0..767
  const int swz = (orig & 7) * 96 + (orig >> 3);          // bijective (768 = 8*96)
  const int m0 = (swz / 24) * 128, n0 = (swz % 24) * 128;
  f32x4 acc[4][4];
#pragma unroll
  for (int m = 0; m < 4; m++)
#pragma unroll
    for (int n = 0; n < 4; n++) acc[m][n] = f32x4{0.f, 0.f, 0.f, 0.f};
  const int w = tid >> 6, lane = tid & 63;
  const int wr = (w >> 1) * 64, wc = (w & 1) * 64;
  const int lrow = lane & 15, lg = lane >> 4;   // fragment row / k-group

  for (int kt = 0; kt < K; kt += 64) {
    __syncthreads();                        // WAR: previous tile fully consumed
#pragma unroll
    for (int i = 0; i < 4; i++) {
      int cl = tid + 256 * i;               // linear chunk: lds byte = cl*16
      int r = cl >> 3, c = cl & 7;
      int sc = (c ^ (r & 7)) * 8;           // XOR-swizzled source col (elements)
      GLD16(A + (size_t)(m0 + r) * K + kt + sc, &As[cl * 8]);
      GLD16(Bt + (size_t)(n0 + r) * K + kt + sc, &Bs[cl * 8]);
    }
    __syncthreads();                        // drains vmcnt: tile resident
#pragma unroll
    for (int kk = 0; kk < 2; kk++) {
      bhalf8 af[4], bfr[4];
#pragma unroll
      for (int m = 0; m < 4; m++) {
        int r = wr + m * 16 + lrow;
        int ch = r * 8 + ((kk * 4 + lg) ^ (r & 7));
        af[m] = *(const bhalf8*)(&As[ch * 8]);
      }
#pragma unroll
      for (int n = 0; n < 4; n++) {
        int r = wc + n * 16 + lrow;
        int ch = r * 8 + ((kk * 4 + lg) ^ (r & 7));
        bfr[n] = *(const bhalf8*)(&Bs[ch * 8]);
      }
#pragma unroll
      for (int m = 0; m < 4; m++)
#pragma unroll
        for (int n = 0; n < 4; n++)
          acc[m][n] = __builtin_amdgcn_mfma_f32_16x16x32_bf16(af[m], bfr[n], acc[m][n], 0, 0, 0);
    }
  }
  const int g = lane >> 4, il = lane & 15;
#pragma unroll
  for (int m = 0; m < 4; m++) {
    int rowb = wr + m * 16 + 4 * g;
#pragma unroll
    for (int n = 0; n < 4; n++) {
      int col = n0 + wc + n * 16 + il;
      float bs = bias[col];
      int which = col >> 10, hh = (col >> 6) & 15, hd = col & 63;
      int row0 = m0 + rowb;
      int b = row0 >> 11, s0 = row0 & 2047;   // 4-row group never crosses b boundary
      if (which == 2) {
        u16x4 pv;
#pragma unroll
        for (int r = 0; r < 4; r++) pv[r] = f2bf(acc[m][n][r] + bs);
        *(u16x4*)(vT + ((size_t)(b * 16 + hh) * HDHD + hd) * SDIM + s0) = pv;
      } else {
#pragma unroll
        for (int r = 0; r < 4; r++) {
          float val = acc[m][n][r] + bs;
          size_t idx = ((size_t)(b * 16 + hh) * SDIM + s0 + r) * HDHD + hd;
          // q pre-scaled by 1/8 * log2(e) so attention can use native exp2
          unsigned short bv = f2bf(which == 0 ? val * 0.1803368801f : val);
          if (which == 0) q[idx] = bv;
          else k[idx] = bv;
        }
      }
    }
  }
}

// ---------------- output GEMM: BM=64, BN=128, 128 threads ----------------
__global__ __launch_bounds__(128) void gemm_out(
    const unsigned short* __restrict__ A, const unsigned short* __restrict__ Bt,
    const float* __restrict__ bias, float* __restrict__ Cf, int M, int N, int K) {
  __shared__ unsigned short As[64][72];
  __shared__ unsigned short Bs[128][72];
  const int tid = threadIdx.x;
  const int orig = blockIdx.y * 8 + blockIdx.x;           // 0..511
  const int swz = (orig & 7) * 64 + (orig >> 3);          // bijective (512 = 8*64)
  const int m0 = (swz / 8) * 64, n0 = (swz % 8) * 128;
  f32x4 acc[4][4];
#pragma unroll
  for (int m = 0; m < 4; m++)
#pragma unroll
    for (int n = 0; n < 4; n++) acc[m][n] = f32x4{0.f, 0.f, 0.f, 0.f};
  const int w = tid >> 6, lane = tid & 63;
  const int wc = w * 64;
  const int lrow = lane & 15, lk = (lane >> 4) * 8;

  for (int kt = 0; kt < K; kt += 64) {
    __syncthreads();
#pragma unroll
    for (int i = 0; i < 4; i++) {           // A: 512 chunks, 4/thread
      int cch = tid + 128 * i;
      int r = cch >> 3, c8 = cch & 7;
      *(u16x8*)(&As[r][c8 * 8]) = *(const u16x8*)(A + (size_t)(m0 + r) * K + kt + c8 * 8);
    }
#pragma unroll
    for (int i = 0; i < 8; i++) {           // B: 1024 chunks, 8/thread
      int cch = tid + 128 * i;
      int r = cch >> 3, c8 = cch & 7;
      *(u16x8*)(&Bs[r][c8 * 8]) = *(const u16x8*)(Bt + (size_t)(n0 + r) * K + kt + c8 * 8);
    }
    __syncthreads();
#pragma unroll
    for (int kk = 0; kk < 2; kk++) {
      bhalf8 af[4], bfr[4];
#pragma unroll
      for (int m = 0; m < 4; m++) af[m] = *(const bhalf8*)(&As[m * 16 + lrow][kk * 32 + lk]);
#pragma unroll
      for (int n = 0; n < 4; n++) bfr[n] = *(const bhalf8*)(&Bs[wc + n * 16 + lrow][kk * 32 + lk]);
#pragma unroll
      for (int m = 0; m < 4; m++)
#pragma unroll
        for (int n = 0; n < 4; n++)
          acc[m][n] = __builtin_amdgcn_mfma_f32_16x16x32_bf16(af[m], bfr[n], acc[m][n], 0, 0, 0);
    }
  }
  const int g = lane >> 4, il = lane & 15;
#pragma unroll
  for (int m = 0; m < 4; m++) {
    int rowb = m * 16 + 4 * g;
#pragma unroll
    for (int n = 0; n < 4; n++) {
      int col = n0 + wc + n * 16 + il;
      float bs = bias[col];
#pragma unroll
      for (int r = 0; r < 4; r++)
        Cf[(size_t)(m0 + rowb + r) * N + col] = acc[m][n][r] + bs;
    }
  }
}

// ============ split-KV causal flash attention, templated segment size ============
// Grid x=bh, y=31-qt, z=seg; FIXED SEGT-tile windows (R11 lesson). P = exp2(s)
// (softmax scale-invariant). V arrives PRE-TRANSPOSED [B,H,HD,S] -> V staging is
// identical in shape to K staging (contiguous b128 loads, zero repack VALU).
// Partials stored UNNORMALIZED (O, l); reduce computes sum(O)/sum(l).
template <int SEGT>
__global__ __launch_bounds__(128, 3) void attn_partial(const unsigned short* __restrict__ Q,
                                                       const unsigned short* __restrict__ Kb,
                                                       const unsigned short* __restrict__ VbT,
                                                       unsigned short* __restrict__ PO,
                                                       float* __restrict__ ML) {
  __shared__ unsigned short Ks[64][72];        // K rows (also reused as O bounce)
  __shared__ unsigned short Vt[64][72];        // V^T rows: Vt[d][k]
  __shared__ unsigned short Ps[2][32][72];     // per-wave P tile (32 q x 64 k)
  const int bh = blockIdx.x;                   // b*16+h
  const int qt = 31 - blockIdx.y;              // longest q-tiles dispatch first
  const int seg = blockIdx.z;
  const int aS = qt / SEGT, bS = qt % SEGT;
  const int nseg = aS + 1;                     // ceil((qt+1)/SEGT)
  if (seg >= nseg) return;
  const int k0 = seg * SEGT;
  const int k1 = min(k0 + SEGT, qt + 1);

  const int tid = threadIdx.x;                 // 0..127
  const int w = tid >> 6, lane = tid & 63;
  const int g = lane >> 4, il = lane & 15;
  const int qbase = qt * 64 + w * 32;          // this wave's 32 q-rows
  const size_t bhS = (size_t)bh * SDIM;

  // Q fragments (pre-scaled by log2e/8): 2 col-frags x 2 d-chunks
  bhalf8 qf[2][2];
#pragma unroll
  for (int f = 0; f < 2; f++) {
    const unsigned short* qp = Q + (bhS + qbase + f * 16 + il) * HDHD + g * 8;
    qf[f][0] = *(const bhalf8*)(qp);
    qf[f][1] = *(const bhalf8*)(qp + 32);
  }
  f32x4 oacc[2][4];                            // O^T[d=df*16+4g+r][q-col]
#pragma unroll
  for (int f = 0; f < 2; f++)
#pragma unroll
    for (int i = 0; i < 4; i++) oacc[f][i] = f32x4{0.f, 0.f, 0.f, 0.f};
  float lrun[2] = {0.f, 0.f};

  // staging indices (128 threads): identical pattern for K and V^T
  const int srow = tid >> 1;                   // row 0..63 (K: s-row; V: d-row)
  const int schk = (tid & 1) * 32;             // 32-u16 half-row

  // ---- prefetch registers: tile k0 ----
  u16x8 kr[4], vrr[4];
  {
    const unsigned short* ksrc = Kb + (bhS + (size_t)k0 * 64 + srow) * HDHD + schk;
#pragma unroll
    for (int i = 0; i < 4; i++) kr[i] = *(const u16x8*)(ksrc + i * 8);
    const unsigned short* vsrc = VbT + ((size_t)bh * HDHD + srow) * SDIM + (size_t)k0 * 64 + schk;
#pragma unroll
    for (int i = 0; i < 4; i++) vrr[i] = *(const u16x8*)(vsrc + i * 8);
  }

  for (int kt = k0; kt < k1; kt++) {
    __syncthreads();
    // --- stage current tile from regs into LDS (K and V^T symmetric) ---
#pragma unroll
    for (int i = 0; i < 4; i++) *(u16x8*)(&Ks[srow][schk + i * 8]) = kr[i];
#pragma unroll
    for (int i = 0; i < 4; i++) *(u16x8*)(&Vt[srow][schk + i * 8]) = vrr[i];
    // --- issue next-tile loads (land during this tile's compute) ---
    if (kt + 1 < k1) {
      const unsigned short* ksrc = Kb + (bhS + (size_t)(kt + 1) * 64 + srow) * HDHD + schk;
#pragma unroll
      for (int i = 0; i < 4; i++) kr[i] = *(const u16x8*)(ksrc + i * 8);
      const unsigned short* vsrc = VbT + ((size_t)bh * HDHD + srow) * SDIM + (size_t)(kt + 1) * 64 + schk;
#pragma unroll
      for (int i = 0; i < 4; i++) vrr[i] = *(const u16x8*)(vsrc + i * 8);
    }
    __syncthreads();
    // --- S^T = mfma(K, Q): lane il holds S^T[k=c*16+4g+r][q=f*16+il] ---
    f32x4 s[2][4];
#pragma unroll
    for (int f = 0; f < 2; f++)
#pragma unroll
      for (int c = 0; c < 4; c++) s[f][c] = f32x4{0.f, 0.f, 0.f, 0.f};
#pragma unroll
    for (int c = 0; c < 4; c++) {
      bhalf8 kf0 = *(const bhalf8*)(&Ks[c * 16 + il][g * 8]);
      bhalf8 kf1 = *(const bhalf8*)(&Ks[c * 16 + il][32 + g * 8]);
#pragma unroll
      for (int f = 0; f < 2; f++) {
        s[f][c] = __builtin_amdgcn_mfma_f32_16x16x32_bf16(kf0, qf[f][0], s[f][c], 0, 0, 0);
        s[f][c] = __builtin_amdgcn_mfma_f32_16x16x32_bf16(kf1, qf[f][1], s[f][c], 0, 0, 0);
      }
    }
    // --- per-lane softmax accumulate (P = exp2(s)) ---
    if (kt == qt) {
      // diagonal tile: causal masking
#pragma unroll
      for (int f = 0; f < 2; f++) {
        const int thr = w * 32 + f * 16 + il;
        float rs = 0.f;
#pragma unroll
        for (int c = 0; c < 4; c++) {
          u16x4 pk;
#pragma unroll
          for (int r = 0; r < 4; r++) {
            float v = s[f][c][r];
            if (c * 16 + 4 * g + r > thr) v = -1e30f;
            float pv = exp2f(v);
            rs += pv;
            pk[r] = f2bfc(pv);
          }
          *(u16x4*)(&Ps[w][f * 16 + il][c * 16 + 4 * g]) = pk;
        }
        rs += __shfl_xor(rs, 16);
        rs += __shfl_xor(rs, 32);
        lrun[f] += rs;
      }
    } else {
      // interior tile: no masking
#pragma unroll
      for (int f = 0; f < 2; f++) {
        float rs = 0.f;
#pragma unroll
        for (int c = 0; c < 4; c++) {
          u16x4 pk;
#pragma unroll
          for (int r = 0; r < 4; r++) {
            float pv = exp2f(s[f][c][r]);
            rs += pv;
            pk[r] = f2bfc(pv);                 // pairs into v_cvt_pk_bf16_f32
          }
          *(u16x4*)(&Ps[w][f * 16 + il][c * 16 + 4 * g]) = pk;
        }
        rs += __shfl_xor(rs, 16);
        rs += __shfl_xor(rs, 32);
        lrun[f] += rs;
      }
    }
    // --- O^T += mfma(V^T, P) ---
#pragma unroll
    for (int kk = 0; kk < 2; kk++) {
      bhalf8 pf0 = *(const bhalf8*)(&Ps[w][il][kk * 32 + g * 8]);
      bhalf8 pf1 = *(const bhalf8*)(&Ps[w][16 + il][kk * 32 + g * 8]);
#pragma unroll
      for (int df = 0; df < 4; df++) {
        bhalf8 vf = *(const bhalf8*)(&Vt[df * 16 + il][kk * 32 + g * 8]);
        oacc[0][df] = __builtin_amdgcn_mfma_f32_16x16x32_bf16(vf, pf0, oacc[0][df], 0, 0, 0);
        oacc[1][df] = __builtin_amdgcn_mfma_f32_16x16x32_bf16(vf, pf1, oacc[1][df], 0, 0, 0);
      }
    }
  }
  // --- epilogue: UNNORMALIZED partial O (via LDS transpose) + l ---
  const int PB = (SEGT == 8) ? 80 : 144;       // per-bh partial count
  const int base = SEGT * (aS * (aS + 1) / 2) + bS * (aS + 1);
  const int pidx = bh * PB + base + seg;
  __syncthreads();
#pragma unroll
  for (int f = 0; f < 2; f++) {
#pragma unroll
    for (int df = 0; df < 4; df++) {
      u16x4 o;
#pragma unroll
      for (int r = 0; r < 4; r++) o[r] = f2bfc(oacc[f][df][r]);
      *(u16x4*)(&Ks[w * 32 + f * 16 + il][df * 16 + 4 * g]) = o;
    }
  }
  if (g == 0) {
#pragma unroll
    for (int f = 0; f < 2; f++)
      ML[(size_t)pidx * 64 + w * 32 + f * 16 + il] = lrun[f];
  }
  __syncthreads();
  {
    const int row = tid >> 1, half = (tid & 1) * 32;
    unsigned short* dst = PO + (size_t)pidx * 4096 + (size_t)row * 64 + half;
#pragma unroll
    for (int c8 = 0; c8 < 4; c8++)
      *(u16x8*)(dst + c8 * 8) = *(const u16x8*)(&Ks[row][half + c8 * 8]);
  }
}

// combine <= 32/SEGT segments per (bh, q-tile): O = sum(O_s) / sum(l_s)
template <int SEGT>
__global__ __launch_bounds__(256) void attn_reduce(const unsigned short* __restrict__ PO,
                                                   const float* __restrict__ ML,
                                                   unsigned short* __restrict__ Om) {
  constexpr int NMAX = 32 / SEGT;
  const int bh = blockIdx.x, qt = blockIdx.y;
  const int aS = qt / SEGT, bS = qt % SEGT;
  const int nseg = aS + 1;
  const int PB = (SEGT == 8) ? 80 : 144;
  const int base = bh * PB + SEGT * (aS * (aS + 1) / 2) + bS * (aS + 1);
  const int t = threadIdx.x;
  const int r = t >> 2, dc = (t & 3) * 16;
  float L = 0.f;
  float O[16];
#pragma unroll
  for (int j = 0; j < 16; j++) O[j] = 0.f;
#pragma unroll
  for (int s = 0; s < NMAX; s++) {
    if (s < nseg) {
      L += ML[(size_t)(base + s) * 64 + r];
      const unsigned short* p = PO + (size_t)(base + s) * 4096 + r * 64 + dc;
      u16x8 p0 = *(const u16x8*)p, p1 = *(const u16x8*)(p + 8);
#pragma unroll
      for (int j = 0; j < 8; j++) O[j] += bf2f(p0[j]);
#pragma unroll
      for (int j = 0; j < 8; j++) O[8 + j] += bf2f(p1[j]);
    }
  }
  float inv = 1.f / L;
  const int b = bh >> 4, h = bh & 15;
  size_t orow = ((size_t)b * SDIM + qt * 64 + r) * DDIM + h * HDHD + dc;
  u16x8 o0, o1;
#pragma unroll
  for (int j = 0; j < 8; j++) o0[j] = f2bfc(O[j] * inv);
#pragma unroll
  for (int j = 0; j < 8; j++) o1[j] = f2bfc(O[8 + j] * inv);
  *(u16x8*)(Om + orow) = o0;
  *(u16x8*)(Om + orow + 8) = o1;
}

// ---- fallback (small ws): direct swapped kernel, P = exp2(s), V^T layout ----
__global__ __launch_bounds__(128, 2) void attn_direct(const unsigned short* __restrict__ Q,
                                                      const unsigned short* __restrict__ Kb,
                                                      const unsigned short* __restrict__ VbT,
                                                      unsigned short* __restrict__ Om) {
  __shared__ unsigned short Ks[64][72];
  __shared__ unsigned short Vt[64][72];
  __shared__ unsigned short Ps[2][32][72];
  const int bh = blockIdx.x;
  const int qt = 31 - blockIdx.y;
  const int tid = threadIdx.x;
  const int w = tid >> 6, lane = tid & 63;
  const int g = lane >> 4, il = lane & 15;
  const int qbase = qt * 64 + w * 32;
  const size_t bhS = (size_t)bh * SDIM;
  bhalf8 qf[2][2];
#pragma unroll
  for (int f = 0; f < 2; f++) {
    const unsigned short* qp = Q + (bhS + qbase + f * 16 + il) * HDHD + g * 8;
    qf[f][0] = *(const bhalf8*)(qp);
    qf[f][1] = *(const bhalf8*)(qp + 32);
  }
  f32x4 oacc[2][4];
#pragma unroll
  for (int f = 0; f < 2; f++)
#pragma unroll
    for (int i = 0; i < 4; i++) oacc[f][i] = f32x4{0.f, 0.f, 0.f, 0.f};
  float lrun[2] = {0.f, 0.f};
  const int srow = tid >> 1, schk = (tid & 1) * 32;
  const int nt = qt + 1;
  for (int kt = 0; kt < nt; kt++) {
    __syncthreads();
    {
      const unsigned short* ksrc = Kb + (bhS + (size_t)kt * 64 + srow) * HDHD + schk;
#pragma unroll
      for (int i = 0; i < 4; i++) *(u16x8*)(&Ks[srow][schk + i * 8]) = *(const u16x8*)(ksrc + i * 8);
      const unsigned short* vsrc = VbT + ((size_t)bh * HDHD + srow) * SDIM + (size_t)kt * 64 + schk;
#pragma unroll
      for (int i = 0; i < 4; i++) *(u16x8*)(&Vt[srow][schk + i * 8]) = *(const u16x8*)(vsrc + i * 8);
    }
    __syncthreads();
    f32x4 s[2][4];
#pragma unroll
    for (int f = 0; f < 2; f++)
#pragma unroll
      for (int c = 0; c < 4; c++) s[f][c] = f32x4{0.f, 0.f, 0.f, 0.f};
#pragma unroll
    for (int c = 0; c < 4; c++) {
      bhalf8 kf0 = *(const bhalf8*)(&Ks[c * 16 + il][g * 8]);
      bhalf8 kf1 = *(const bhalf8*)(&Ks[c * 16 + il][32 + g * 8]);
#pragma unroll
      for (int f = 0; f < 2; f++) {
        s[f][c] = __builtin_amdgcn_mfma_f32_16x16x32_bf16(kf0, qf[f][0], s[f][c], 0, 0, 0);
        s[f][c] = __builtin_amdgcn_mfma_f32_16x16x32_bf16(kf1, qf[f][1], s[f][c], 0, 0, 0);
      }
    }
    const bool diag = (kt == qt);
#pragma unroll
    for (int f = 0; f < 2; f++) {
      const int thr = w * 32 + f * 16 + il;
      float rs = 0.f;
#pragma unroll
      for (int c = 0; c < 4; c++) {
        u16x4 pk;
#pragma unroll
        for (int r = 0; r < 4; r++) {
          float v = s[f][c][r];
          if (diag && (c * 16 + 4 * g + r > thr)) v = -1e30f;
          float pv = exp2f(v);
          rs += pv;
          pk[r] = f2bfc(pv);
        }
        *(u16x4*)(&Ps[w][f * 16 + il][c * 16 + 4 * g]) = pk;
      }
      rs += __shfl_xor(rs, 16);
      rs += __shfl_xor(rs, 32);
      lrun[f] += rs;
    }
#pragma unroll
    for (int kk = 0; kk < 2; kk++) {
      bhalf8 pf0 = *(const bhalf8*)(&Ps[w][il][kk * 32 + g * 8]);
      bhalf8 pf1 = *(const bhalf8*)(&Ps[w][16 + il][kk * 32 + g * 8]);
#pragma unroll
      for (int df = 0; df < 4; df++) {
        bhalf8 vf = *(const bhalf8*)(&Vt[df * 16 + il][kk * 32 + g * 8]);
        oacc[0][df] = __builtin_amdgcn_mfma_f32_16x16x32_bf16(vf, pf0, oacc[0][df], 0, 0, 0);
        oacc[1][df] = __builtin_amdgcn_mfma_f32_16x16x32_bf16(vf, pf1, oacc[1][df], 0, 0, 0);
      }
    }
  }
  __syncthreads();
#pragma unroll
  for (int f = 0; f < 2; f++) {
    float inv = 1.f / lrun[f];
#pragma unroll
    for (int df = 0; df < 4; df++) {
      u16x4 o;
#pragma unroll
      for (int r = 0; r < 4; r++) o[r] = f2bfc(oacc[f][df][r] * inv);
      *(u16x4*)(&Ks[w * 32 + f * 16 + il][df * 16 + 4 * g]) = o;
    }
  }
  __syncthreads();
  {
    const int row = tid >> 1, half = (tid & 1) * 32;
    const int b = bh >> 4, h = bh & 15;
    size_t obase = ((size_t)b * SDIM + qt * 64 + row) * DDIM + h * HDHD + half;
#pragma unroll
    for (int c8 = 0; c8 < 4; c8++)
      *(u16x8*)(Om + obase + c8 * 8) = *(const u16x8*)(&Ks[row][half + c8 * 8]);
  }
}

extern "C" void kernel_launch(void* const* d_in, const int* in_sizes, int n_in,
                              void* d_out, int out_size, void* d_ws, size_t ws_size,
                              hipStream_t stream) {
  const float* hidden = (const float*)d_in[0];
  const float* attn_w = (const float*)d_in[1];
  const float* attn_b = (const float*)d_in[2];
  const float* proj_w = (const float*)d_in[3];
  const float* proj_b = (const float*)d_in[4];
  const float* projectors = (const float*)d_in[5];
  float* out = (float*)d_out;
  char* ws = (char*)d_ws;
  (void)in_sizes; (void)n_in; (void)out_size;

  unsigned short* hseq   = (unsigned short*)(ws);               // [4096][1024] bf16  8 MB
  unsigned short* wqkvT  = (unsigned short*)(ws + 8388608);     // [3072][1024] bf16  6 MB
  unsigned short* qb     = (unsigned short*)(ws + 14680064);    // [B,H,S,HD] bf16    8 MB
  unsigned short* kb     = (unsigned short*)(ws + 23068672);    // 8 MB
  unsigned short* vbT    = (unsigned short*)(ws + 31457280);    // [B,H,HD,S] bf16    8 MB
  unsigned short* attnM  = (unsigned short*)(ws + 39845888);    // [4096][1024] bf16  8 MB
  unsigned short* wprojT = (unsigned short*)(ws + 48234496);    // [1024][1024] bf16  2 MB
  unsigned short* PO     = (unsigned short*)(ws + 50331648);    // partials (bf16)
  float* ML8 = (float*)(ws + 71303168);
  float* ML4 = (float*)(ws + 88080384);
  const size_t need8 = 71303168ull + 655360ull;
  const size_t need4 = 88080384ull + 1179648ull;

  cvt_hidden<<<dim3(4096), dim3(256), 0, stream>>>(hidden, hseq);
  transpose_cvt<<<dim3(32, 96), dim3(256), 0, stream>>>(attn_w, wqkvT, 1024, 3072);
  make_wproj<<<dim3(16, 16), dim3(256), 0, stream>>>(projectors, proj_w, wprojT);
  gemm_qkv<<<dim3(24, 32), dim3(256), 0, stream>>>(hseq, wqkvT, attn_b,
                                                   qb, kb, vbT, 4096, 3072, 1024);
  if (ws_size >= need4) {
    attn_partial<4><<<dim3(32, 32, 8), dim3(128), 0, stream>>>(qb, kb, vbT, PO, ML4);
    attn_reduce<4><<<dim3(32, 32), dim3(256), 0, stream>>>(PO, ML4, attnM);
  } else if (ws_size >= need8) {
    attn_partial<8><<<dim3(32, 32, 4), dim3(128), 0, stream>>>(qb, kb, vbT, PO, ML8);
    attn_reduce<8><<<dim3(32, 32), dim3(256), 0, stream>>>(PO, ML8, attnM);
  } else {
    attn_direct<<<dim3(32, 32), dim3(128), 0, stream>>>(qb, kb, vbT, attnM);
  }
  gemm_out<<<dim3(8, 64), dim3(128), 0, stream>>>(attnM, wprojT, proj_b, out,
                                                  4096, 1024, 1024);
}

// Round 21
// 151.355 us; speedup vs baseline: 1.0397x; 1.0163x over previous
//
#include <hip/hip_runtime.h>
#include <hip/hip_bf16.h>

typedef __attribute__((ext_vector_type(8))) short bhalf8;   // 8 bf16 MFMA operand
typedef __attribute__((ext_vector_type(4))) float f32x4;
typedef __attribute__((ext_vector_type(8))) unsigned short u16x8;
typedef __attribute__((ext_vector_type(4))) unsigned short u16x4;

#define BDIM 2
#define SDIM 2048
#define DDIM 1024
#define HDIM 16
#define HDHD 64

// async global->LDS, 16B per lane; LDS dest is wave-uniform base + lane*16 (linear).
#define GLD16(gaddr, laddr)                                                          \
  __builtin_amdgcn_global_load_lds(                                                  \
      (const __attribute__((address_space(1))) unsigned int*)(gaddr),                \
      (__attribute__((address_space(3))) unsigned int*)(laddr), 16, 0, 0)

__device__ __forceinline__ unsigned short f2bf(float f) {
  unsigned u = __builtin_bit_cast(unsigned, f);
  u += 0x7fffu + ((u >> 16) & 1u);           // RNE
  return (unsigned short)(u >> 16);
}
// compiler-visible RNE cvt -> pairs into v_cvt_pk_bf16_f32 (m240: don't hand-write asm)
__device__ __forceinline__ unsigned short f2bfc(float f) {
  return __builtin_bit_cast(unsigned short, __float2bfloat16(f));
}
__device__ __forceinline__ float bf2f(unsigned short u) {
  return __builtin_bit_cast(float, (unsigned)u << 16);
}

// ---- fused: cvt_hidden (bid<4096) | transpose_cvt W[1024][3072]->Wt (bid>=4096) ----
// One launch instead of two: independent BW-bound phases co-schedule across CUs.
// LDS = transpose's 4.2 KB only (no occupancy impact on cvt blocks).
__global__ __launch_bounds__(256) void prep_ct(const float* __restrict__ hidden,
                                               unsigned short* __restrict__ hseq,
                                               const float* __restrict__ attn_w,
                                               unsigned short* __restrict__ wqkvT) {
  __shared__ float tl[32][33];
  const int bid = blockIdx.x;
  const int t = threadIdx.x;
  if (bid < 4096) {
    size_t i = ((size_t)bid * 256 + t) * 4;
    f32x4 v = *(const f32x4*)(hidden + i);
    u16x4 o;
    o[0] = f2bf(v[0]); o[1] = f2bf(v[1]); o[2] = f2bf(v[2]); o[3] = f2bf(v[3]);
    *(u16x4*)(hseq + i) = o;
  } else {
    const int tt = bid - 4096;                 // 0..3071
    const int rt = (tt & 31) * 32, ct = (tt >> 5) * 32;
    const int r8 = t >> 5, c = t & 31;
#pragma unroll
    for (int i = 0; i < 4; i++)
      tl[r8 + i * 8][c] = attn_w[(size_t)(rt + r8 + i * 8) * 3072 + ct + c];
    __syncthreads();
#pragma unroll
    for (int i = 0; i < 4; i++)
      wqkvT[(size_t)(ct + r8 + i * 8) * 1024 + rt + c] = f2bf(tl[c][r8 + i * 8]);
  }
}

// ------- W'^T[o][h*64+d] = sum_e P[h][d][e] * Wproj[h*64+e][o]  (bf16 out) -------
__global__ __launch_bounds__(256) void make_wproj(const float* __restrict__ proj,
                                                  const float* __restrict__ wproj,
                                                  unsigned short* __restrict__ WT) {
  int h = blockIdx.x, ot = blockIdx.y * 64;
  __shared__ float Pl[64][65];
  __shared__ float Wl[64][65];
  int t = threadIdx.x;
#pragma unroll
  for (int i = 0; i < 16; i++) {
    int idx = t + 256 * i;                  // 0..4095
    int a = idx >> 6, bc = idx & 63;
    Pl[a][bc] = proj[(size_t)h * 4096 + idx];
    Wl[a][bc] = wproj[(size_t)(h * 64 + a) * 1024 + ot + bc];
  }
  __syncthreads();
  int d = t & 63, ob = t >> 6;              // lanes vary d -> coalesced writes
#pragma unroll
  for (int i = 0; i < 16; i++) {
    int o = ob + i * 4;
    float acc = 0.f;
#pragma unroll
    for (int e = 0; e < 64; e++) acc += Pl[d][e] * Wl[e][o];
    WT[(size_t)(ot + o) * 1024 + h * 64 + d] = f2bf(acc);
  }
}

// ---------------- QKV GEMM: C[M,N]=A[M,K]@Bt[N,K]^T+bias, split into q/k/vT ----------------
// R10-proven: GLD16 staging, linear LDS, XOR-swizzled source + reads (conflict-free, R16 PMC).
// V is stored TRANSPOSED [B,H,HD,S]: per fragment the 4 rows are 4 consecutive s at fixed
// (h,hd) -> one packed u16x4 store, and attention stages V^T with zero repack VALU.
__global__ __launch_bounds__(256) void gemm_qkv(
    const unsigned short* __restrict__ A, const unsigned short* __restrict__ Bt,
    const float* __restrict__ bias,
    unsigned short* __restrict__ q, unsigned short* __restrict__ k,
    unsigned short* __restrict__ vT, int M, int N, int K) {
  __shared__ unsigned short As[128 * 64];      // physically linear; logically swizzled
  __shared__ unsigned short Bs[128 * 64];
  const int tid = threadIdx.x;
  const int orig = blockIdx.y * 24 + blockIdx.x;          // 0..767
  const int swz = (orig & 7) * 96 + (orig >> 3);          // bijective (768 = 8*96)
  const int m0 = (swz / 24) * 128, n0 = (swz % 24) * 128;
  f32x4 acc[4][4];
#pragma unroll
  for (int m = 0; m < 4; m++)
#pragma unroll
    for (int n = 0; n < 4; n++) acc[m][n] = f32x4{0.f, 0.f, 0.f, 0.f};
  const int w = tid >> 6, lane = tid & 63;
  const int wr = (w >> 1) * 64, wc = (w & 1) * 64;
  const int lrow = lane & 15, lg = lane >> 4;   // fragment row / k-group

  for (int kt = 0; kt < K; kt += 64) {
    __syncthreads();                        // WAR: previous tile fully consumed
#pragma unroll
    for (int i = 0; i < 4; i++) {
      int cl = tid + 256 * i;               // linear chunk: lds byte = cl*16
      int r = cl >> 3, c = cl & 7;
      int sc = (c ^ (r & 7)) * 8;           // XOR-swizzled source col (elements)
      GLD16(A + (size_t)(m0 + r) * K + kt + sc, &As[cl * 8]);
      GLD16(Bt + (size_t)(n0 + r) * K + kt + sc, &Bs[cl * 8]);
    }
    __syncthreads();                        // drains vmcnt: tile resident
#pragma unroll
    for (int kk = 0; kk < 2; kk++) {
      bhalf8 af[4], bfr[4];
#pragma unroll
      for (int m = 0; m < 4; m++) {
        int r = wr + m * 16 + lrow;
        int ch = r * 8 + ((kk * 4 + lg) ^ (r & 7));
        af[m] = *(const bhalf8*)(&As[ch * 8]);
      }
#pragma unroll
      for (int n = 0; n < 4; n++) {
        int r = wc + n * 16 + lrow;
        int ch = r * 8 + ((kk * 4 + lg) ^ (r & 7));
        bfr[n] = *(const bhalf8*)(&Bs[ch * 8]);
      }
#pragma unroll
      for (int m = 0; m < 4; m++)
#pragma unroll
        for (int n = 0; n < 4; n++)
          acc[m][n] = __builtin_amdgcn_mfma_f32_16x16x32_bf16(af[m], bfr[n], acc[m][n], 0, 0, 0);
    }
  }
  const int g = lane >> 4, il = lane & 15;
#pragma unroll
  for (int m = 0; m < 4; m++) {
    int rowb = wr + m * 16 + 4 * g;
#pragma unroll
    for (int n = 0; n < 4; n++) {
      int col = n0 + wc + n * 16 + il;
      float bs = bias[col];
      int which = col >> 10, hh = (col >> 6) & 15, hd = col & 63;
      int row0 = m0 + rowb;
      int b = row0 >> 11, s0 = row0 & 2047;   // 4-row group never crosses b boundary
      if (which == 2) {
        u16x4 pv;
#pragma unroll
        for (int r = 0; r < 4; r++) pv[r] = f2bf(acc[m][n][r] + bs);
        *(u16x4*)(vT + ((size_t)(b * 16 + hh) * HDHD + hd) * SDIM + s0) = pv;
      } else {
#pragma unroll
        for (int r = 0; r < 4; r++) {
          float val = acc[m][n][r] + bs;
          size_t idx = ((size_t)(b * 16 + hh) * SDIM + s0 + r) * HDHD + hd;
          // q pre-scaled by 1/8 * log2(e) so attention can use native exp2
          unsigned short bv = f2bf(which == 0 ? val * 0.1803368801f : val);
          if (which == 0) q[idx] = bv;
          else k[idx] = bv;
        }
      }
    }
  }
}

// ---------------- output GEMM: BM=64, BN=128, 128 threads ----------------
__global__ __launch_bounds__(128) void gemm_out(
    const unsigned short* __restrict__ A, const unsigned short* __restrict__ Bt,
    const float* __restrict__ bias, float* __restrict__ Cf, int M, int N, int K) {
  __shared__ unsigned short As[64][72];
  __shared__ unsigned short Bs[128][72];
  const int tid = threadIdx.x;
  const int orig = blockIdx.y * 8 + blockIdx.x;           // 0..511
  const int swz = (orig & 7) * 64 + (orig >> 3);          // bijective (512 = 8*64)
  const int m0 = (swz / 8) * 64, n0 = (swz % 8) * 128;
  f32x4 acc[4][4];
#pragma unroll
  for (int m = 0; m < 4; m++)
#pragma unroll
    for (int n = 0; n < 4; n++) acc[m][n] = f32x4{0.f, 0.f, 0.f, 0.f};
  const int w = tid >> 6, lane = tid & 63;
  const int wc = w * 64;
  const int lrow = lane & 15, lk = (lane >> 4) * 8;

  for (int kt = 0; kt < K; kt += 64) {
    __syncthreads();
#pragma unroll
    for (int i = 0; i < 4; i++) {           // A: 512 chunks, 4/thread
      int cch = tid + 128 * i;
      int r = cch >> 3, c8 = cch & 7;
      *(u16x8*)(&As[r][c8 * 8]) = *(const u16x8*)(A + (size_t)(m0 + r) * K + kt + c8 * 8);
    }
#pragma unroll
    for (int i = 0; i < 8; i++) {           // B: 1024 chunks, 8/thread
      int cch = tid + 128 * i;
      int r = cch >> 3, c8 = cch & 7;
      *(u16x8*)(&Bs[r][c8 * 8]) = *(const u16x8*)(Bt + (size_t)(n0 + r) * K + kt + c8 * 8);
    }
    __syncthreads();
#pragma unroll
    for (int kk = 0; kk < 2; kk++) {
      bhalf8 af[4], bfr[4];
#pragma unroll
      for (int m = 0; m < 4; m++) af[m] = *(const bhalf8*)(&As[m * 16 + lrow][kk * 32 + lk]);
#pragma unroll
      for (int n = 0; n < 4; n++) bfr[n] = *(const bhalf8*)(&Bs[wc + n * 16 + lrow][kk * 32 + lk]);
#pragma unroll
      for (int m = 0; m < 4; m++)
#pragma unroll
        for (int n = 0; n < 4; n++)
          acc[m][n] = __builtin_amdgcn_mfma_f32_16x16x32_bf16(af[m], bfr[n], acc[m][n], 0, 0, 0);
    }
  }
  const int g = lane >> 4, il = lane & 15;
#pragma unroll
  for (int m = 0; m < 4; m++) {
    int rowb = m * 16 + 4 * g;
#pragma unroll
    for (int n = 0; n < 4; n++) {
      int col = n0 + wc + n * 16 + il;
      float bs = bias[col];
#pragma unroll
      for (int r = 0; r < 4; r++)
        Cf[(size_t)(m0 + rowb + r) * N + col] = acc[m][n][r] + bs;
    }
  }
}

// ============ split-KV causal flash attention, templated segment size ============
// Grid x=bh, y=31-qt, z=seg; FIXED SEGT-tile windows (R11 lesson). P = exp2(s)
// (softmax scale-invariant). V arrives PRE-TRANSPOSED [B,H,HD,S] -> V staging is
// identical in shape to K staging (contiguous b128 loads, zero repack VALU).
// Partials stored UNNORMALIZED (O, l); reduce computes sum(O)/sum(l).
template <int SEGT>
__global__ __launch_bounds__(128, 3) void attn_partial(const unsigned short* __restrict__ Q,
                                                       const unsigned short* __restrict__ Kb,
                                                       const unsigned short* __restrict__ VbT,
                                                       unsigned short* __restrict__ PO,
                                                       float* __restrict__ ML) {
  __shared__ unsigned short Ks[64][72];        // K rows (also reused as O bounce)
  __shared__ unsigned short Vt[64][72];        // V^T rows: Vt[d][k]
  __shared__ unsigned short Ps[2][32][72];     // per-wave P tile (32 q x 64 k)
  const int bh = blockIdx.x;                   // b*16+h
  const int qt = 31 - blockIdx.y;              // longest q-tiles dispatch first
  const int seg = blockIdx.z;
  const int aS = qt / SEGT, bS = qt % SEGT;
  const int nseg = aS + 1;                     // ceil((qt+1)/SEGT)
  if (seg >= nseg) return;
  const int k0 = seg * SEGT;
  const int k1 = min(k0 + SEGT, qt + 1);

  const int tid = threadIdx.x;                 // 0..127
  const int w = tid >> 6, lane = tid & 63;
  const int g = lane >> 4, il = lane & 15;
  const int qbase = qt * 64 + w * 32;          // this wave's 32 q-rows
  const size_t bhS = (size_t)bh * SDIM;

  // Q fragments (pre-scaled by log2e/8): 2 col-frags x 2 d-chunks
  bhalf8 qf[2][2];
#pragma unroll
  for (int f = 0; f < 2; f++) {
    const unsigned short* qp = Q + (bhS + qbase + f * 16 + il) * HDHD + g * 8;
    qf[f][0] = *(const bhalf8*)(qp);
    qf[f][1] = *(const bhalf8*)(qp + 32);
  }
  f32x4 oacc[2][4];                            // O^T[d=df*16+4g+r][q-col]
#pragma unroll
  for (int f = 0; f < 2; f++)
#pragma unroll
    for (int i = 0; i < 4; i++) oacc[f][i] = f32x4{0.f, 0.f, 0.f, 0.f};
  float lrun[2] = {0.f, 0.f};

  // staging indices (128 threads): identical pattern for K and V^T
  const int srow = tid >> 1;                   // row 0..63 (K: s-row; V: d-row)
  const int schk = (tid & 1) * 32;             // 32-u16 half-row

  // ---- prefetch registers: tile k0 ----
  u16x8 kr[4], vrr[4];
  {
    const unsigned short* ksrc = Kb + (bhS + (size_t)k0 * 64 + srow) * HDHD + schk;
#pragma unroll
    for (int i = 0; i < 4; i++) kr[i] = *(const u16x8*)(ksrc + i * 8);
    const unsigned short* vsrc = VbT + ((size_t)bh * HDHD + srow) * SDIM + (size_t)k0 * 64 + schk;
#pragma unroll
    for (int i = 0; i < 4; i++) vrr[i] = *(const u16x8*)(vsrc + i * 8);
  }

  for (int kt = k0; kt < k1; kt++) {
    __syncthreads();
    // --- stage current tile from regs into LDS (K and V^T symmetric) ---
#pragma unroll
    for (int i = 0; i < 4; i++) *(u16x8*)(&Ks[srow][schk + i * 8]) = kr[i];
#pragma unroll
    for (int i = 0; i < 4; i++) *(u16x8*)(&Vt[srow][schk + i * 8]) = vrr[i];
    // --- issue next-tile loads (land during this tile's compute) ---
    if (kt + 1 < k1) {
      const unsigned short* ksrc = Kb + (bhS + (size_t)(kt + 1) * 64 + srow) * HDHD + schk;
#pragma unroll
      for (int i = 0; i < 4; i++) kr[i] = *(const u16x8*)(ksrc + i * 8);
      const unsigned short* vsrc = VbT + ((size_t)bh * HDHD + srow) * SDIM + (size_t)(kt + 1) * 64 + schk;
#pragma unroll
      for (int i = 0; i < 4; i++) vrr[i] = *(const u16x8*)(vsrc + i * 8);
    }
    __syncthreads();
    // --- S^T = mfma(K, Q): lane il holds S^T[k=c*16+4g+r][q=f*16+il] ---
    f32x4 s[2][4];
#pragma unroll
    for (int f = 0; f < 2; f++)
#pragma unroll
      for (int c = 0; c < 4; c++) s[f][c] = f32x4{0.f, 0.f, 0.f, 0.f};
#pragma unroll
    for (int c = 0; c < 4; c++) {
      bhalf8 kf0 = *(const bhalf8*)(&Ks[c * 16 + il][g * 8]);
      bhalf8 kf1 = *(const bhalf8*)(&Ks[c * 16 + il][32 + g * 8]);
#pragma unroll
      for (int f = 0; f < 2; f++) {
        s[f][c] = __builtin_amdgcn_mfma_f32_16x16x32_bf16(kf0, qf[f][0], s[f][c], 0, 0, 0);
        s[f][c] = __builtin_amdgcn_mfma_f32_16x16x32_bf16(kf1, qf[f][1], s[f][c], 0, 0, 0);
      }
    }
    // --- per-lane softmax accumulate (P = exp2(s)) ---
    if (kt == qt) {
      // diagonal tile: causal masking
#pragma unroll
      for (int f = 0; f < 2; f++) {
        const int thr = w * 32 + f * 16 + il;
        float rs = 0.f;
#pragma unroll
        for (int c = 0; c < 4; c++) {
          u16x4 pk;
#pragma unroll
          for (int r = 0; r < 4; r++) {
            float v = s[f][c][r];
            if (c * 16 + 4 * g + r > thr) v = -1e30f;
            float pv = exp2f(v);
            rs += pv;
            pk[r] = f2bfc(pv);
          }
          *(u16x4*)(&Ps[w][f * 16 + il][c * 16 + 4 * g]) = pk;
        }
        rs += __shfl_xor(rs, 16);
        rs += __shfl_xor(rs, 32);
        lrun[f] += rs;
      }
    } else {
      // interior tile: no masking
#pragma unroll
      for (int f = 0; f < 2; f++) {
        float rs = 0.f;
#pragma unroll
        for (int c = 0; c < 4; c++) {
          u16x4 pk;
#pragma unroll
          for (int r = 0; r < 4; r++) {
            float pv = exp2f(s[f][c][r]);
            rs += pv;
            pk[r] = f2bfc(pv);                 // pairs into v_cvt_pk_bf16_f32
          }
          *(u16x4*)(&Ps[w][f * 16 + il][c * 16 + 4 * g]) = pk;
        }
        rs += __shfl_xor(rs, 16);
        rs += __shfl_xor(rs, 32);
        lrun[f] += rs;
      }
    }
    // --- O^T += mfma(V^T, P) ---
#pragma unroll
    for (int kk = 0; kk < 2; kk++) {
      bhalf8 pf0 = *(const bhalf8*)(&Ps[w][il][kk * 32 + g * 8]);
      bhalf8 pf1 = *(const bhalf8*)(&Ps[w][16 + il][kk * 32 + g * 8]);
#pragma unroll
      for (int df = 0; df < 4; df++) {
        bhalf8 vf = *(const bhalf8*)(&Vt[df * 16 + il][kk * 32 + g * 8]);
        oacc[0][df] = __builtin_amdgcn_mfma_f32_16x16x32_bf16(vf, pf0, oacc[0][df], 0, 0, 0);
        oacc[1][df] = __builtin_amdgcn_mfma_f32_16x16x32_bf16(vf, pf1, oacc[1][df], 0, 0, 0);
      }
    }
  }
  // --- epilogue: UNNORMALIZED partial O (via LDS transpose) + l ---
  const int PB = (SEGT == 8) ? 80 : 144;       // per-bh partial count
  const int base = SEGT * (aS * (aS + 1) / 2) + bS * (aS + 1);
  const int pidx = bh * PB + base + seg;
  __syncthreads();
#pragma unroll
  for (int f = 0; f < 2; f++) {
#pragma unroll
    for (int df = 0; df < 4; df++) {
      u16x4 o;
#pragma unroll
      for (int r = 0; r < 4; r++) o[r] = f2bfc(oacc[f][df][r]);
      *(u16x4*)(&Ks[w * 32 + f * 16 + il][df * 16 + 4 * g]) = o;
    }
  }
  if (g == 0) {
#pragma unroll
    for (int f = 0; f < 2; f++)
      ML[(size_t)pidx * 64 + w * 32 + f * 16 + il] = lrun[f];
  }
  __syncthreads();
  {
    const int row = tid >> 1, half = (tid & 1) * 32;
    unsigned short* dst = PO + (size_t)pidx * 4096 + (size_t)row * 64 + half;
#pragma unroll
    for (int c8 = 0; c8 < 4; c8++)
      *(u16x8*)(dst + c8 * 8) = *(const u16x8*)(&Ks[row][half + c8 * 8]);
  }
}

// combine <= 32/SEGT segments per (bh, q-tile): O = sum(O_s) / sum(l_s)
template <int SEGT>
__global__ __launch_bounds__(256) void attn_reduce(const unsigned short* __restrict__ PO,
                                                   const float* __restrict__ ML,
                                                   unsigned short* __restrict__ Om) {
  constexpr int NMAX = 32 / SEGT;
  const int bh = blockIdx.x, qt = blockIdx.y;
  const int aS = qt / SEGT, bS = qt % SEGT;
  const int nseg = aS + 1;
  const int PB = (SEGT == 8) ? 80 : 144;
  const int base = bh * PB + SEGT * (aS * (aS + 1) / 2) + bS * (aS + 1);
  const int t = threadIdx.x;
  const int r = t >> 2, dc = (t & 3) * 16;
  float L = 0.f;
  float O[16];
#pragma unroll
  for (int j = 0; j < 16; j++) O[j] = 0.f;
#pragma unroll
  for (int s = 0; s < NMAX; s++) {
    if (s < nseg) {
      L += ML[(size_t)(base + s) * 64 + r];
      const unsigned short* p = PO + (size_t)(base + s) * 4096 + r * 64 + dc;
      u16x8 p0 = *(const u16x8*)p, p1 = *(const u16x8*)(p + 8);
#pragma unroll
      for (int j = 0; j < 8; j++) O[j] += bf2f(p0[j]);
#pragma unroll
      for (int j = 0; j < 8; j++) O[8 + j] += bf2f(p1[j]);
    }
  }
  float inv = 1.f / L;
  const int b = bh >> 4, h = bh & 15;
  size_t orow = ((size_t)b * SDIM + qt * 64 + r) * DDIM + h * HDHD + dc;
  u16x8 o0, o1;
#pragma unroll
  for (int j = 0; j < 8; j++) o0[j] = f2bfc(O[j] * inv);
#pragma unroll
  for (int j = 0; j < 8; j++) o1[j] = f2bfc(O[8 + j] * inv);
  *(u16x8*)(Om + orow) = o0;
  *(u16x8*)(Om + orow + 8) = o1;
}

// ---- fallback (small ws): direct swapped kernel, P = exp2(s), V^T layout ----
__global__ __launch_bounds__(128, 2) void attn_direct(const unsigned short* __restrict__ Q,
                                                      const unsigned short* __restrict__ Kb,
                                                      const unsigned short* __restrict__ VbT,
                                                      unsigned short* __restrict__ Om) {
  __shared__ unsigned short Ks[64][72];
  __shared__ unsigned short Vt[64][72];
  __shared__ unsigned short Ps[2][32][72];
  const int bh = blockIdx.x;
  const int qt = 31 - blockIdx.y;
  const int tid = threadIdx.x;
  const int w = tid >> 6, lane = tid & 63;
  const int g = lane >> 4, il = lane & 15;
  const int qbase = qt * 64 + w * 32;
  const size_t bhS = (size_t)bh * SDIM;
  bhalf8 qf[2][2];
#pragma unroll
  for (int f = 0; f < 2; f++) {
    const unsigned short* qp = Q + (bhS + qbase + f * 16 + il) * HDHD + g * 8;
    qf[f][0] = *(const bhalf8*)(qp);
    qf[f][1] = *(const bhalf8*)(qp + 32);
  }
  f32x4 oacc[2][4];
#pragma unroll
  for (int f = 0; f < 2; f++)
#pragma unroll
    for (int i = 0; i < 4; i++) oacc[f][i] = f32x4{0.f, 0.f, 0.f, 0.f};
  float lrun[2] = {0.f, 0.f};
  const int srow = tid >> 1, schk = (tid & 1) * 32;
  const int nt = qt + 1;
  for (int kt = 0; kt < nt; kt++) {
    __syncthreads();
    {
      const unsigned short* ksrc = Kb + (bhS + (size_t)kt * 64 + srow) * HDHD + schk;
#pragma unroll
      for (int i = 0; i < 4; i++) *(u16x8*)(&Ks[srow][schk + i * 8]) = *(const u16x8*)(ksrc + i * 8);
      const unsigned short* vsrc = VbT + ((size_t)bh * HDHD + srow) * SDIM + (size_t)kt * 64 + schk;
#pragma unroll
      for (int i = 0; i < 4; i++) *(u16x8*)(&Vt[srow][schk + i * 8]) = *(const u16x8*)(vsrc + i * 8);
    }
    __syncthreads();
    f32x4 s[2][4];
#pragma unroll
    for (int f = 0; f < 2; f++)
#pragma unroll
      for (int c = 0; c < 4; c++) s[f][c] = f32x4{0.f, 0.f, 0.f, 0.f};
#pragma unroll
    for (int c = 0; c < 4; c++) {
      bhalf8 kf0 = *(const bhalf8*)(&Ks[c * 16 + il][g * 8]);
      bhalf8 kf1 = *(const bhalf8*)(&Ks[c * 16 + il][32 + g * 8]);
#pragma unroll
      for (int f = 0; f < 2; f++) {
        s[f][c] = __builtin_amdgcn_mfma_f32_16x16x32_bf16(kf0, qf[f][0], s[f][c], 0, 0, 0);
        s[f][c] = __builtin_amdgcn_mfma_f32_16x16x32_bf16(kf1, qf[f][1], s[f][c], 0, 0, 0);
      }
    }
    const bool diag = (kt == qt);
#pragma unroll
    for (int f = 0; f < 2; f++) {
      const int thr = w * 32 + f * 16 + il;
      float rs = 0.f;
#pragma unroll
      for (int c = 0; c < 4; c++) {
        u16x4 pk;
#pragma unroll
        for (int r = 0; r < 4; r++) {
          float v = s[f][c][r];
          if (diag && (c * 16 + 4 * g + r > thr)) v = -1e30f;
          float pv = exp2f(v);
          rs += pv;
          pk[r] = f2bfc(pv);
        }
        *(u16x4*)(&Ps[w][f * 16 + il][c * 16 + 4 * g]) = pk;
      }
      rs += __shfl_xor(rs, 16);
      rs += __shfl_xor(rs, 32);
      lrun[f] += rs;
    }
#pragma unroll
    for (int kk = 0; kk < 2; kk++) {
      bhalf8 pf0 = *(const bhalf8*)(&Ps[w][il][kk * 32 + g * 8]);
      bhalf8 pf1 = *(const bhalf8*)(&Ps[w][16 + il][kk * 32 + g * 8]);
#pragma unroll
      for (int df = 0; df < 4; df++) {
        bhalf8 vf = *(const bhalf8*)(&Vt[df * 16 + il][kk * 32 + g * 8]);
        oacc[0][df] = __builtin_amdgcn_mfma_f32_16x16x32_bf16(vf, pf0, oacc[0][df], 0, 0, 0);
        oacc[1][df] = __builtin_amdgcn_mfma_f32_16x16x32_bf16(vf, pf1, oacc[1][df], 0, 0, 0);
      }
    }
  }
  __syncthreads();
#pragma unroll
  for (int f = 0; f < 2; f++) {
    float inv = 1.f / lrun[f];
#pragma unroll
    for (int df = 0; df < 4; df++) {
      u16x4 o;
#pragma unroll
      for (int r = 0; r < 4; r++) o[r] = f2bfc(oacc[f][df][r] * inv);
      *(u16x4*)(&Ks[w * 32 + f * 16 + il][df * 16 + 4 * g]) = o;
    }
  }
  __syncthreads();
  {
    const int row = tid >> 1, half = (tid & 1) * 32;
    const int b = bh >> 4, h = bh & 15;
    size_t obase = ((size_t)b * SDIM + qt * 64 + row) * DDIM + h * HDHD + half;
#pragma unroll
    for (int c8 = 0; c8 < 4; c8++)
      *(u16x8*)(Om + obase + c8 * 8) = *(const u16x8*)(&Ks[row][half + c8 * 8]);
  }
}

extern "C" void kernel_launch(void* const* d_in, const int* in_sizes, int n_in,
                              void* d_out, int out_size, void* d_ws, size_t ws_size,
                              hipStream_t stream) {
  const float* hidden = (const float*)d_in[0];
  const float* attn_w = (const float*)d_in[1];
  const float* attn_b = (const float*)d_in[2];
  const float* proj_w = (const float*)d_in[3];
  const float* proj_b = (const float*)d_in[4];
  const float* projectors = (const float*)d_in[5];
  float* out = (float*)d_out;
  char* ws = (char*)d_ws;
  (void)in_sizes; (void)n_in; (void)out_size;

  unsigned short* hseq   = (unsigned short*)(ws);               // [4096][1024] bf16  8 MB
  unsigned short* wqkvT  = (unsigned short*)(ws + 8388608);     // [3072][1024] bf16  6 MB
  unsigned short* qb     = (unsigned short*)(ws + 14680064);    // [B,H,S,HD] bf16    8 MB
  unsigned short* kb     = (unsigned short*)(ws + 23068672);    // 8 MB
  unsigned short* vbT    = (unsigned short*)(ws + 31457280);    // [B,H,HD,S] bf16    8 MB
  unsigned short* attnM  = (unsigned short*)(ws + 39845888);    // [4096][1024] bf16  8 MB
  unsigned short* wprojT = (unsigned short*)(ws + 48234496);    // [1024][1024] bf16  2 MB
  unsigned short* PO     = (unsigned short*)(ws + 50331648);    // partials (bf16)
  float* ML8 = (float*)(ws + 71303168);
  float* ML4 = (float*)(ws + 88080384);
  const size_t need8 = 71303168ull + 655360ull;
  const size_t need4 = 88080384ull + 1179648ull;

  prep_ct<<<dim3(7168), dim3(256), 0, stream>>>(hidden, hseq, attn_w, wqkvT);
  make_wproj<<<dim3(16, 16), dim3(256), 0, stream>>>(projectors, proj_w, wprojT);
  gemm_qkv<<<dim3(24, 32), dim3(256), 0, stream>>>(hseq, wqkvT, attn_b,
                                                   qb, kb, vbT, 4096, 3072, 1024);
  if (ws_size >= need4) {
    attn_partial<4><<<dim3(32, 32, 8), dim3(128), 0, stream>>>(qb, kb, vbT, PO, ML4);
    attn_reduce<4><<<dim3(32, 32), dim3(256), 0, stream>>>(PO, ML4, attnM);
  } else if (ws_size >= need8) {
    attn_partial<8><<<dim3(32, 32, 4), dim3(128), 0, stream>>>(qb, kb, vbT, PO, ML8);
    attn_reduce<8><<<dim3(32, 32), dim3(256), 0, stream>>>(PO, ML8, attnM);
  } else {
    attn_direct<<<dim3(32, 32), dim3(128), 0, stream>>>(qb, kb, vbT, attnM);
  }
  gemm_out<<<dim3(8, 64), dim3(128), 0, stream>>>(attnM, wprojT, proj_b, out,
                                                  4096, 1024, 1024);
}